// Round 2
// baseline (1340.361 us; speedup 1.0000x reference)
//
#include <hip/hip_runtime.h>
#include <math.h>

#define NH 16
#define KD 64
#define DMODEL 1024
#define BATCH 2
#define SEQ 2048
#define MROWS (BATCH*SEQ)

// ---------------------------------------------------------------------------
// RoPE tables: sin[s][i], cos[s][i], i in [0,32)
// angle = s * exp(2i * (-ln(10000)/64))
// ---------------------------------------------------------------------------
__global__ __launch_bounds__(256) void k_rope_tables(float* __restrict__ sin_t,
                                                     float* __restrict__ cos_t) {
    int idx = blockIdx.x * 256 + threadIdx.x;
    if (idx >= SEQ * 32) return;
    int s = idx >> 5, i = idx & 31;
    float invf = expf((float)(2 * i) * (-logf(10000.0f) / (float)KD));
    float ang = (float)s * invf;
    sin_t[idx] = sinf(ang);
    cos_t[idx] = cosf(ang);
}

// ---------------------------------------------------------------------------
// Tiled fp32 GEMM: C[M,N] = A[M,K] @ W[K,N] + bias, optional RoPE epilogue.
// BM=BN=64, BK=32, 256 threads, 4x4 microtile per thread.
// Thread (tx,ty): rows m0+ty*4+i, cols n0 + tx + 16*j  (j=0..3).
// With n0 head-aligned (64-wide tiles), RoPE pairs (d,d+32) are intra-thread:
// (tx <-> tx+32) = (j0,j2), (tx+16 <-> tx+48) = (j1,j3).
// ---------------------------------------------------------------------------
template<bool ROPE>
__global__ __launch_bounds__(256) void k_gemm64(const float* __restrict__ A,
                                                const float* __restrict__ W,
                                                const float* __restrict__ bias,
                                                float* __restrict__ C,
                                                const float* __restrict__ sin_t,
                                                const float* __restrict__ cos_t) {
    __shared__ float As[32][65];   // [kk][m] (transposed)
    __shared__ float Ws[32][68];   // [kk][n], padded to keep float4 writes aligned
    const int tid = threadIdx.x;
    const int tx = tid & 15, ty = tid >> 4;
    const int n0 = blockIdx.x * 64;
    const int m0 = blockIdx.y * 64;

    float acc[4][4] = {};

    for (int k0 = 0; k0 < DMODEL; k0 += 32) {
        // A tile: 64 rows x 32 cols = 512 float4, 2 per thread (transposed into LDS)
#pragma unroll
        for (int it = 0; it < 2; ++it) {
            int idx = tid + it * 256;      // 0..511
            int row = idx >> 3;            // 0..63
            int c4  = idx & 7;             // 0..7
            const float4 av = *reinterpret_cast<const float4*>(
                &A[(size_t)(m0 + row) * DMODEL + k0 + c4 * 4]);
            As[c4 * 4 + 0][row] = av.x;
            As[c4 * 4 + 1][row] = av.y;
            As[c4 * 4 + 2][row] = av.z;
            As[c4 * 4 + 3][row] = av.w;
        }
        // W tile: 32 rows x 64 cols = 512 float4, 2 per thread
#pragma unroll
        for (int it = 0; it < 2; ++it) {
            int idx = tid + it * 256;
            int row = idx >> 4;            // 0..31
            int c4  = idx & 15;            // 0..15
            const float4 wv = *reinterpret_cast<const float4*>(
                &W[(size_t)(k0 + row) * DMODEL + n0 + c4 * 4]);
            *reinterpret_cast<float4*>(&Ws[row][c4 * 4]) = wv;
        }
        __syncthreads();
#pragma unroll
        for (int kk = 0; kk < 32; ++kk) {
            float a[4], w[4];
#pragma unroll
            for (int i = 0; i < 4; ++i) a[i] = As[kk][ty * 4 + i];
#pragma unroll
            for (int j = 0; j < 4; ++j) w[j] = Ws[kk][tx + 16 * j];
#pragma unroll
            for (int i = 0; i < 4; ++i)
#pragma unroll
                for (int j = 0; j < 4; ++j)
                    acc[i][j] = fmaf(a[i], w[j], acc[i][j]);
        }
        __syncthreads();
    }

    // epilogue: bias (+ RoPE), store
#pragma unroll
    for (int i = 0; i < 4; ++i) {
        int r = m0 + ty * 4 + i;
        int srow = r & (SEQ - 1);          // r % SEQ
        float c0 = acc[i][0] + bias[n0 + tx];
        float c1 = acc[i][1] + bias[n0 + tx + 16];
        float c2 = acc[i][2] + bias[n0 + tx + 32];
        float c3 = acc[i][3] + bias[n0 + tx + 48];
        if (ROPE) {
            float s0 = sin_t[srow * 32 + tx],      q0 = cos_t[srow * 32 + tx];
            float s1 = sin_t[srow * 32 + tx + 16], q1 = cos_t[srow * 32 + tx + 16];
            float o0 = q0 * c0 - s0 * c2;
            float o2 = s0 * c0 + q0 * c2;
            float o1 = q1 * c1 - s1 * c3;
            float o3 = s1 * c1 + q1 * c3;
            c0 = o0; c1 = o1; c2 = o2; c3 = o3;
        }
        size_t base = (size_t)r * DMODEL + n0;
        C[base + tx]      = c0;
        C[base + tx + 16] = c1;
        C[base + tx + 32] = c2;
        C[base + tx + 48] = c3;
    }
}

// ---------------------------------------------------------------------------
// Flash attention, fp32. One block per (b, h, 64-row Q tile).
// 256 threads: thread (tx,ty) owns score rows ty*4+i, score cols tx*4+j.
// Online softmax; PV accumulated via LDS-staged P.
// ---------------------------------------------------------------------------
__global__ __launch_bounds__(256) void k_attn(const float* __restrict__ q,
                                              const float* __restrict__ k,
                                              const float* __restrict__ v,
                                              float* __restrict__ ctx) {
    __shared__ float Qs[64][65];
    __shared__ float Ks[64][65];
    __shared__ float Vs[64][65];
    __shared__ float Ps[64][65];
    const int tid = threadIdx.x;
    const int tx = tid & 15, ty = tid >> 4;
    const int qt = blockIdx.x & 31;            // S/64 = 32 tiles
    const int h  = (blockIdx.x >> 5) & 15;
    const int b  = blockIdx.x >> 9;
    const int q0 = qt * 64;

    // load Q tile (pre-scaled by 1/sqrt(D) = 1/8)
#pragma unroll
    for (int it = 0; it < 4; ++it) {
        int idx = tid + it * 256;      // 0..1023
        int row = idx >> 4;            // 0..63
        int c4  = idx & 15;            // 0..15
        const float4 qv = *reinterpret_cast<const float4*>(
            &q[(size_t)(((b * SEQ) + (q0 + row)) * NH + h) * KD + c4 * 4]);
        Qs[row][c4 * 4 + 0] = qv.x * 0.125f;
        Qs[row][c4 * 4 + 1] = qv.y * 0.125f;
        Qs[row][c4 * 4 + 2] = qv.z * 0.125f;
        Qs[row][c4 * 4 + 3] = qv.w * 0.125f;
    }

    float m[4], l[4], acc[4][4];
#pragma unroll
    for (int i = 0; i < 4; ++i) {
        m[i] = -3.4e38f; l[i] = 0.f;
#pragma unroll
        for (int j = 0; j < 4; ++j) acc[i][j] = 0.f;
    }
    __syncthreads();

    for (int t0 = 0; t0 < SEQ; t0 += 64) {
        // load K,V tiles
#pragma unroll
        for (int it = 0; it < 4; ++it) {
            int idx = tid + it * 256;
            int row = idx >> 4;
            int c4  = idx & 15;
            size_t g = (size_t)(((b * SEQ) + (t0 + row)) * NH + h) * KD + c4 * 4;
            const float4 kv = *reinterpret_cast<const float4*>(&k[g]);
            Ks[row][c4 * 4 + 0] = kv.x;
            Ks[row][c4 * 4 + 1] = kv.y;
            Ks[row][c4 * 4 + 2] = kv.z;
            Ks[row][c4 * 4 + 3] = kv.w;
            const float4 vv = *reinterpret_cast<const float4*>(&v[g]);
            Vs[row][c4 * 4 + 0] = vv.x;
            Vs[row][c4 * 4 + 1] = vv.y;
            Vs[row][c4 * 4 + 2] = vv.z;
            Vs[row][c4 * 4 + 3] = vv.w;
        }
        __syncthreads();

        // scores: sc[i][j] = (q/8) . k   (64-deep)
        float sc[4][4] = {};
#pragma unroll
        for (int kk = 0; kk < 64; ++kk) {
            float qv[4], kv[4];
#pragma unroll
            for (int i = 0; i < 4; ++i) qv[i] = Qs[ty * 4 + i][kk];
#pragma unroll
            for (int j = 0; j < 4; ++j) kv[j] = Ks[tx * 4 + j][kk];
#pragma unroll
            for (int i = 0; i < 4; ++i)
#pragma unroll
                for (int j = 0; j < 4; ++j)
                    sc[i][j] = fmaf(qv[i], kv[j], sc[i][j]);
        }

        // online softmax update (row reduce over 16 tx lanes)
#pragma unroll
        for (int i = 0; i < 4; ++i) {
            float rm = fmaxf(fmaxf(sc[i][0], sc[i][1]), fmaxf(sc[i][2], sc[i][3]));
#pragma unroll
            for (int msk = 1; msk < 16; msk <<= 1)
                rm = fmaxf(rm, __shfl_xor(rm, msk));
            float mnew = fmaxf(m[i], rm);
            float alpha = expf(m[i] - mnew);
            float rsum = 0.f;
#pragma unroll
            for (int j = 0; j < 4; ++j) {
                float p = expf(sc[i][j] - mnew);
                Ps[ty * 4 + i][tx * 4 + j] = p;
                rsum += p;
            }
#pragma unroll
            for (int msk = 1; msk < 16; msk <<= 1)
                rsum += __shfl_xor(rsum, msk);
            l[i] = l[i] * alpha + rsum;
            m[i] = mnew;
#pragma unroll
            for (int j = 0; j < 4; ++j) acc[i][j] *= alpha;
        }
        __syncthreads();

        // PV: acc[i][j] += P[row][t] * V[t][tx*4+j]
#pragma unroll 8
        for (int t = 0; t < 64; ++t) {
            float pv[4], vv[4];
#pragma unroll
            for (int i = 0; i < 4; ++i) pv[i] = Ps[ty * 4 + i][t];
#pragma unroll
            for (int j = 0; j < 4; ++j) vv[j] = Vs[t][tx * 4 + j];
#pragma unroll
            for (int i = 0; i < 4; ++i)
#pragma unroll
                for (int j = 0; j < 4; ++j)
                    acc[i][j] = fmaf(pv[i], vv[j], acc[i][j]);
        }
        __syncthreads();
    }

    // normalize + store ctx in [B,S,H,D] layout (== [M][DMODEL])
#pragma unroll
    for (int i = 0; i < 4; ++i) {
        int r = q0 + ty * 4 + i;
        float inv = 1.0f / l[i];
        float4 o;
        o.x = acc[i][0] * inv;
        o.y = acc[i][1] * inv;
        o.z = acc[i][2] * inv;
        o.w = acc[i][3] * inv;
        *reinterpret_cast<float4*>(
            &ctx[(size_t)(((b * SEQ) + r) * NH + h) * KD + tx * 4]) = o;
    }
}

// ---------------------------------------------------------------------------
extern "C" void kernel_launch(void* const* d_in, const int* in_sizes, int n_in,
                              void* d_out, int out_size, void* d_ws, size_t ws_size,
                              hipStream_t stream) {
    const float* x  = (const float*)d_in[0];
    const float* Wq = (const float*)d_in[1];
    const float* bq = (const float*)d_in[2];
    const float* Wk = (const float*)d_in[3];
    const float* bk = (const float*)d_in[4];
    const float* Wv = (const float*)d_in[5];
    const float* bv = (const float*)d_in[6];
    const float* Wo = (const float*)d_in[7];
    const float* bo = (const float*)d_in[8];
    float* out = (float*)d_out;

    float* ws    = (float*)d_ws;
    float* sin_t = ws;                       // SEQ*32
    float* cos_t = sin_t + SEQ * 32;         // SEQ*32
    float* qb    = cos_t + SEQ * 32;         // MROWS*DMODEL
    float* kb    = qb + (size_t)MROWS * DMODEL;
    float* vb    = kb + (size_t)MROWS * DMODEL;
    float* cb    = vb + (size_t)MROWS * DMODEL;

    k_rope_tables<<<(SEQ * 32 + 255) / 256, 256, 0, stream>>>(sin_t, cos_t);

    dim3 grid(DMODEL / 64, MROWS / 64);
    k_gemm64<true ><<<grid, 256, 0, stream>>>(x, Wq, bq, qb, sin_t, cos_t);
    k_gemm64<true ><<<grid, 256, 0, stream>>>(x, Wk, bk, kb, sin_t, cos_t);
    k_gemm64<false><<<grid, 256, 0, stream>>>(x, Wv, bv, vb, nullptr, nullptr);

    k_attn<<<BATCH * NH * (SEQ / 64), 256, 0, stream>>>(qb, kb, vb, cb);

    k_gemm64<false><<<grid, 256, 0, stream>>>(cb, Wo, bo, out, nullptr, nullptr);
}

// Round 3
// 745.947 us; speedup vs baseline: 1.7969x; 1.7969x over previous
//
#include <hip/hip_runtime.h>
#include <math.h>

#define NH 16
#define KD 64
#define DMODEL 1024
#define BATCH 2
#define SEQ 2048
#define MROWS (BATCH*SEQ)

typedef float f32x4 __attribute__((ext_vector_type(4)));
typedef __bf16 bf16x8 __attribute__((ext_vector_type(8)));

__device__ inline unsigned short f2bf(float x) {
    union { float f; unsigned u; } a; a.f = x;
    unsigned r = a.u + 0x7fffu + ((a.u >> 16) & 1u);
    return (unsigned short)(r >> 16);
}
__device__ inline float bf2f(unsigned short h) {
    union { unsigned u; float f; } a; a.u = ((unsigned)h) << 16; return a.f;
}

// ---------------------------------------------------------------------------
// RoPE tables: sin[s][i], cos[s][i], i in [0,32)
// ---------------------------------------------------------------------------
__global__ __launch_bounds__(256) void k_rope_tables(float* __restrict__ sin_t,
                                                     float* __restrict__ cos_t) {
    int idx = blockIdx.x * 256 + threadIdx.x;
    if (idx >= SEQ * 32) return;
    int s = idx >> 5, i = idx & 31;
    float invf = expf((float)(2 * i) * (-logf(10000.0f) / (float)KD));
    float ang = (float)s * invf;
    sin_t[idx] = sinf(ang);
    cos_t[idx] = cosf(ang);
}

// ---------------------------------------------------------------------------
// Tiled fp32 GEMM: C = A@W + bias. BM=BN=64, BK=32, 256 thr, 4x4 microtile.
// MODE 0: fp32 C out (O proj)
// MODE 1: RoPE + 0.125 scale -> bf16 hi/lo [b,s,h,d]   (Q)
// MODE 2: RoPE            -> bf16 hi/lo [b,s,h,d]      (K)
// MODE 3: plain           -> bf16 hi/lo [b,h,d,s] (transposed) (V)
// ---------------------------------------------------------------------------
template<int MODE>
__global__ __launch_bounds__(256) void k_gemm64(const float* __restrict__ A,
                                                const float* __restrict__ W,
                                                const float* __restrict__ bias,
                                                float* __restrict__ C,
                                                unsigned short* __restrict__ Ohi,
                                                unsigned short* __restrict__ Olo,
                                                const float* __restrict__ sin_t,
                                                const float* __restrict__ cos_t) {
    __shared__ float As[32][65];
    __shared__ float Ws[32][68];
    const int tid = threadIdx.x;
    const int tx = tid & 15, ty = tid >> 4;
    const int n0 = blockIdx.x * 64;
    const int m0 = blockIdx.y * 64;

    float acc[4][4] = {};

    for (int k0 = 0; k0 < DMODEL; k0 += 32) {
#pragma unroll
        for (int it = 0; it < 2; ++it) {
            int idx = tid + it * 256;
            int row = idx >> 3;
            int c4  = idx & 7;
            const float4 av = *reinterpret_cast<const float4*>(
                &A[(size_t)(m0 + row) * DMODEL + k0 + c4 * 4]);
            As[c4 * 4 + 0][row] = av.x;
            As[c4 * 4 + 1][row] = av.y;
            As[c4 * 4 + 2][row] = av.z;
            As[c4 * 4 + 3][row] = av.w;
        }
#pragma unroll
        for (int it = 0; it < 2; ++it) {
            int idx = tid + it * 256;
            int row = idx >> 4;
            int c4  = idx & 15;
            const float4 wv = *reinterpret_cast<const float4*>(
                &W[(size_t)(k0 + row) * DMODEL + n0 + c4 * 4]);
            *reinterpret_cast<float4*>(&Ws[row][c4 * 4]) = wv;
        }
        __syncthreads();
#pragma unroll
        for (int kk = 0; kk < 32; ++kk) {
            float a[4], w[4];
#pragma unroll
            for (int i = 0; i < 4; ++i) a[i] = As[kk][ty * 4 + i];
#pragma unroll
            for (int j = 0; j < 4; ++j) w[j] = Ws[kk][tx + 16 * j];
#pragma unroll
            for (int i = 0; i < 4; ++i)
#pragma unroll
                for (int j = 0; j < 4; ++j)
                    acc[i][j] = fmaf(a[i], w[j], acc[i][j]);
        }
        __syncthreads();
    }

#pragma unroll
    for (int i = 0; i < 4; ++i) {
        int r = m0 + ty * 4 + i;
        int srow = r & (SEQ - 1);
        float c0 = acc[i][0] + bias[n0 + tx];
        float c1 = acc[i][1] + bias[n0 + tx + 16];
        float c2 = acc[i][2] + bias[n0 + tx + 32];
        float c3 = acc[i][3] + bias[n0 + tx + 48];
        if (MODE == 1 || MODE == 2) {
            float s0 = sin_t[srow * 32 + tx],      q0 = cos_t[srow * 32 + tx];
            float s1 = sin_t[srow * 32 + tx + 16], q1 = cos_t[srow * 32 + tx + 16];
            float o0 = q0 * c0 - s0 * c2;
            float o2 = s0 * c0 + q0 * c2;
            float o1 = q1 * c1 - s1 * c3;
            float o3 = s1 * c1 + q1 * c3;
            c0 = o0; c1 = o1; c2 = o2; c3 = o3;
        }
        if (MODE == 1) { c0 *= 0.125f; c1 *= 0.125f; c2 *= 0.125f; c3 *= 0.125f; }
        if (MODE == 0) {
            size_t base = (size_t)r * DMODEL + n0;
            C[base + tx]      = c0;
            C[base + tx + 16] = c1;
            C[base + tx + 32] = c2;
            C[base + tx + 48] = c3;
        } else {
            float cv[4] = { c0, c1, c2, c3 };
            if (MODE == 3) {
                int b = r >> 11;           // r / SEQ
                int s = srow;
                int h = n0 >> 6;
#pragma unroll
                for (int j = 0; j < 4; ++j) {
                    int d = tx + 16 * j;
                    size_t o = ((size_t)((b * NH + h) * KD + d)) * SEQ + s;
                    unsigned short hi = f2bf(cv[j]);
                    Ohi[o] = hi;
                    Olo[o] = f2bf(cv[j] - bf2f(hi));
                }
            } else {
                size_t base = (size_t)r * DMODEL + n0;
#pragma unroll
                for (int j = 0; j < 4; ++j) {
                    size_t o = base + tx + 16 * j;
                    unsigned short hi = f2bf(cv[j]);
                    Ohi[o] = hi;
                    Olo[o] = f2bf(cv[j] - bf2f(hi));
                }
            }
        }
    }
}

// ---------------------------------------------------------------------------
// Flash attention, bf16-split MFMA. Block = 256 thr (4 waves), 64 q-rows.
// Wave w owns q rows [w*16, w*16+16). KV tiles of 64.
// QK^T: 3 MFMAs (qh*kh + qh*kl + ql*kh); PV: 2 MFMAs (p*vh + p*vl).
// mfma_f32_16x16x32_bf16 layouts:
//   A: lane l -> row l&15,  k = (l>>4)*8 + j
//   B: lane l -> col l&15,  k = (l>>4)*8 + j
//   D: lane l -> col l&15,  row = (l>>4)*4 + reg
// LDS tiles XOR-swizzled: elem ^= (row&7)<<3  (byte ^ (row&7)<<4).
// ---------------------------------------------------------------------------
__global__ __launch_bounds__(256) void k_attn(const unsigned short* __restrict__ qhi,
                                              const unsigned short* __restrict__ qlo,
                                              const unsigned short* __restrict__ khi,
                                              const unsigned short* __restrict__ klo,
                                              const unsigned short* __restrict__ vthi,
                                              const unsigned short* __restrict__ vtlo,
                                              float* __restrict__ ctx) {
    __shared__ unsigned short Kh[64 * 64];
    __shared__ unsigned short Kl[64 * 64];
    __shared__ unsigned short Vh[64 * 64];   // [d][t]
    __shared__ unsigned short Vl[64 * 64];
    __shared__ unsigned short Ps[4][16 * 64];

    const int tid  = threadIdx.x;
    const int lane = tid & 63;
    const int w    = tid >> 6;

    // XCD-chunked swizzle (1024 blocks, 8 XCDs, 128 each)
    int bid = blockIdx.x;
    int wg  = (bid & 7) * 128 + (bid >> 3);
    const int qt = wg & 31;
    const int h  = (wg >> 5) & 15;
    const int b  = wg >> 9;
    const int q0 = qt * 64;

    // Q fragments in registers (hi/lo, 2 k-steps); Q pre-scaled by 1/8.
    bf16x8 qh[2], ql[2];
    {
        size_t qbase = ((size_t)(b * SEQ + q0 + w * 16 + (lane & 15)) * NH + h) * KD
                       + ((lane >> 4) * 8);
        qh[0] = *reinterpret_cast<const bf16x8*>(qhi + qbase);
        qh[1] = *reinterpret_cast<const bf16x8*>(qhi + qbase + 32);
        ql[0] = *reinterpret_cast<const bf16x8*>(qlo + qbase);
        ql[1] = *reinterpret_cast<const bf16x8*>(qlo + qbase + 32);
    }

    f32x4 ctxa[4];
    float m_r[4], l_r[4];
#pragma unroll
    for (int nf = 0; nf < 4; ++nf) ctxa[nf] = (f32x4){0.f, 0.f, 0.f, 0.f};
#pragma unroll
    for (int r = 0; r < 4; ++r) { m_r[r] = -1e30f; l_r[r] = 0.f; }

    for (int t0 = 0; t0 < SEQ; t0 += 64) {
        // stage K hi/lo [t][d] and V hi/lo [d][t] into LDS, swizzled
#pragma unroll
        for (int it = 0; it < 2; ++it) {
            int idx = tid + it * 256;       // 0..511
            int row = idx >> 3;             // 0..63
            int c8  = (idx & 7) * 8;        // 0..56
            int sw  = c8 ^ ((row & 7) << 3);
            size_t gk = ((size_t)(b * SEQ + t0 + row) * NH + h) * KD + c8;
            *reinterpret_cast<bf16x8*>(&Kh[row * 64 + sw]) =
                *reinterpret_cast<const bf16x8*>(khi + gk);
            *reinterpret_cast<bf16x8*>(&Kl[row * 64 + sw]) =
                *reinterpret_cast<const bf16x8*>(klo + gk);
            size_t gv = ((size_t)((b * NH + h) * KD + row)) * SEQ + t0 + c8;
            *reinterpret_cast<bf16x8*>(&Vh[row * 64 + sw]) =
                *reinterpret_cast<const bf16x8*>(vthi + gv);
            *reinterpret_cast<bf16x8*>(&Vl[row * 64 + sw]) =
                *reinterpret_cast<const bf16x8*>(vtlo + gv);
        }
        __syncthreads();

        // ---- QK^T (split 3-MFMA) ----
        f32x4 s[4];
#pragma unroll
        for (int nf = 0; nf < 4; ++nf) s[nf] = (f32x4){0.f, 0.f, 0.f, 0.f};
#pragma unroll
        for (int nf = 0; nf < 4; ++nf) {
#pragma unroll
            for (int ks = 0; ks < 2; ++ks) {
                int trow = nf * 16 + (lane & 15);
                int koff = trow * 64 + ((ks * 32 + (lane >> 4) * 8) ^ ((trow & 7) << 3));
                bf16x8 kh = *reinterpret_cast<const bf16x8*>(&Kh[koff]);
                bf16x8 kl = *reinterpret_cast<const bf16x8*>(&Kl[koff]);
                s[nf] = __builtin_amdgcn_mfma_f32_16x16x32_bf16(ql[ks], kh, s[nf], 0, 0, 0);
                s[nf] = __builtin_amdgcn_mfma_f32_16x16x32_bf16(qh[ks], kl, s[nf], 0, 0, 0);
                s[nf] = __builtin_amdgcn_mfma_f32_16x16x32_bf16(qh[ks], kh, s[nf], 0, 0, 0);
            }
        }

        // ---- online softmax (rows live in 16-lane groups) ----
        float alpha[4];
#pragma unroll
        for (int r = 0; r < 4; ++r) {
            float rm = fmaxf(fmaxf(s[0][r], s[1][r]), fmaxf(s[2][r], s[3][r]));
            rm = fmaxf(rm, __shfl_xor(rm, 1));
            rm = fmaxf(rm, __shfl_xor(rm, 2));
            rm = fmaxf(rm, __shfl_xor(rm, 4));
            rm = fmaxf(rm, __shfl_xor(rm, 8));
            float mn = fmaxf(m_r[r], rm);
            float al = __expf(m_r[r] - mn);
            float rs = 0.f;
            int qloc = (lane >> 4) * 4 + r;
#pragma unroll
            for (int nf = 0; nf < 4; ++nf) {
                float p = __expf(s[nf][r] - mn);
                rs += p;
                int t = nf * 16 + (lane & 15);
                Ps[w][qloc * 64 + (t ^ ((qloc & 7) << 3))] = f2bf(p);
            }
            rs += __shfl_xor(rs, 1);
            rs += __shfl_xor(rs, 2);
            rs += __shfl_xor(rs, 4);
            rs += __shfl_xor(rs, 8);
            m_r[r] = mn;
            l_r[r] = l_r[r] * al + rs;
            alpha[r] = al;
        }
#pragma unroll
        for (int nf = 0; nf < 4; ++nf)
#pragma unroll
            for (int r = 0; r < 4; ++r) ctxa[nf][r] *= alpha[r];

        // ---- PV (P bf16, V split 2-MFMA) ----
#pragma unroll
        for (int ks = 0; ks < 2; ++ks) {
            int qrow = lane & 15;
            int aoff = qrow * 64 + ((ks * 32 + (lane >> 4) * 8) ^ ((qrow & 7) << 3));
            bf16x8 pa = *reinterpret_cast<const bf16x8*>(&Ps[w][aoff]);
#pragma unroll
            for (int nf = 0; nf < 4; ++nf) {
                int drow = nf * 16 + (lane & 15);
                int voff = drow * 64 + ((ks * 32 + (lane >> 4) * 8) ^ ((drow & 7) << 3));
                bf16x8 vh = *reinterpret_cast<const bf16x8*>(&Vh[voff]);
                bf16x8 vl = *reinterpret_cast<const bf16x8*>(&Vl[voff]);
                ctxa[nf] = __builtin_amdgcn_mfma_f32_16x16x32_bf16(pa, vh, ctxa[nf], 0, 0, 0);
                ctxa[nf] = __builtin_amdgcn_mfma_f32_16x16x32_bf16(pa, vl, ctxa[nf], 0, 0, 0);
            }
        }
        __syncthreads();
    }

    // ---- normalize + store ctx fp32 [b,s,h,d] ----
#pragma unroll
    for (int nf = 0; nf < 4; ++nf) {
#pragma unroll
        for (int r = 0; r < 4; ++r) {
            int qloc = (lane >> 4) * 4 + r;
            int qg = q0 + w * 16 + qloc;
            int d = nf * 16 + (lane & 15);
            ctx[((size_t)(b * SEQ + qg) * NH + h) * KD + d] = ctxa[nf][r] / l_r[r];
        }
    }
}

// ---------------------------------------------------------------------------
extern "C" void kernel_launch(void* const* d_in, const int* in_sizes, int n_in,
                              void* d_out, int out_size, void* d_ws, size_t ws_size,
                              hipStream_t stream) {
    const float* x  = (const float*)d_in[0];
    const float* Wq = (const float*)d_in[1];
    const float* bq = (const float*)d_in[2];
    const float* Wk = (const float*)d_in[3];
    const float* bk = (const float*)d_in[4];
    const float* Wv = (const float*)d_in[5];
    const float* bv = (const float*)d_in[6];
    const float* Wo = (const float*)d_in[7];
    const float* bo = (const float*)d_in[8];
    float* out = (float*)d_out;

    const size_t NE = (size_t)MROWS * DMODEL;   // 4M elements
    float* ws    = (float*)d_ws;
    float* sin_t = ws;                           // SEQ*32
    float* cos_t = sin_t + SEQ * 32;
    unsigned short* qhi  = (unsigned short*)(cos_t + SEQ * 32);
    unsigned short* qlo  = qhi  + NE;
    unsigned short* khi_ = qlo  + NE;
    unsigned short* klo_ = khi_ + NE;
    unsigned short* vthi = klo_ + NE;
    unsigned short* vtlo = vthi + NE;
    float* cb = (float*)(vtlo + NE);             // ctx fp32

    k_rope_tables<<<(SEQ * 32 + 255) / 256, 256, 0, stream>>>(sin_t, cos_t);

    dim3 grid(DMODEL / 64, MROWS / 64);
    k_gemm64<1><<<grid, 256, 0, stream>>>(x, Wq, bq, nullptr, qhi, qlo, sin_t, cos_t);
    k_gemm64<2><<<grid, 256, 0, stream>>>(x, Wk, bk, nullptr, khi_, klo_, sin_t, cos_t);
    k_gemm64<3><<<grid, 256, 0, stream>>>(x, Wv, bv, nullptr, vthi, vtlo, nullptr, nullptr);

    k_attn<<<BATCH * NH * (SEQ / 64), 256, 0, stream>>>(qhi, qlo, khi_, klo_, vthi, vtlo, cb);

    k_gemm64<0><<<grid, 256, 0, stream>>>(cb, Wo, bo, out, nullptr, nullptr, nullptr, nullptr);
}

// Round 4
// 300.041 us; speedup vs baseline: 4.4673x; 2.4861x over previous
//
#include <hip/hip_runtime.h>
#include <math.h>

#define NH 16
#define KD 64
#define DMODEL 1024
#define BATCH 2
#define SEQ 2048
#define MROWS (BATCH*SEQ)

typedef float f32x4 __attribute__((ext_vector_type(4)));
typedef __bf16 bf16x8 __attribute__((ext_vector_type(8)));

__device__ __forceinline__ unsigned short f2bf(float x) {
    union { float f; unsigned u; } a; a.f = x;
    unsigned r = a.u + 0x7fffu + ((a.u >> 16) & 1u);
    return (unsigned short)(r >> 16);
}
__device__ __forceinline__ float bf2f(unsigned short h) {
    union { unsigned u; float f; } a; a.u = ((unsigned)h) << 16; return a.f;
}

// async global->LDS, 16B per lane. LDS dst must be wave-uniform; global src per-lane.
__device__ __forceinline__ void gl2lds16(const void* gsrc, void* ldst) {
    __builtin_amdgcn_global_load_lds(
        (const __attribute__((address_space(1))) void*)gsrc,
        (__attribute__((address_space(3))) void*)ldst, 16, 0, 0);
}

// ---------------------------------------------------------------------------
// RoPE tables
// ---------------------------------------------------------------------------
__global__ __launch_bounds__(256) void k_rope_tables(float* __restrict__ sin_t,
                                                     float* __restrict__ cos_t) {
    int idx = blockIdx.x * 256 + threadIdx.x;
    if (idx >= SEQ * 32) return;
    int s = idx >> 5, i = idx & 31;
    float invf = expf((float)(2 * i) * (-logf(10000.0f) / (float)KD));
    float ang = (float)s * invf;
    sin_t[idx] = sinf(ang);
    cos_t[idx] = cosf(ang);
}

// ---------------------------------------------------------------------------
// x (fp32, row-major) -> hi/lo bf16, same layout
// ---------------------------------------------------------------------------
__global__ __launch_bounds__(256) void k_cvt_x(const float* __restrict__ x,
                                               unsigned short* __restrict__ xh,
                                               unsigned short* __restrict__ xl) {
    int idx = blockIdx.x * 256 + threadIdx.x;   // float4 index
    float4 v = reinterpret_cast<const float4*>(x)[idx];
    ushort4 h, l;
    h.x = f2bf(v.x); l.x = f2bf(v.x - bf2f(h.x));
    h.y = f2bf(v.y); l.y = f2bf(v.y - bf2f(h.y));
    h.z = f2bf(v.z); l.z = f2bf(v.z - bf2f(h.z));
    h.w = f2bf(v.w); l.w = f2bf(v.w - bf2f(h.w));
    reinterpret_cast<ushort4*>(xh)[idx] = h;
    reinterpret_cast<ushort4*>(xl)[idx] = l;
}

// ---------------------------------------------------------------------------
// W [k][n] fp32 -> Wt [n][k] bf16 hi/lo (64x64 LDS tile transpose)
// ---------------------------------------------------------------------------
__global__ __launch_bounds__(256) void k_cvt_wT(const float* __restrict__ W,
                                                unsigned short* __restrict__ Th,
                                                unsigned short* __restrict__ Tl) {
    __shared__ float L[64][65];
    const int tid = threadIdx.x;
    const int n0 = blockIdx.x * 64, k0 = blockIdx.y * 64;
#pragma unroll
    for (int it = 0; it < 4; ++it) {
        int idx = tid + it * 256;      // 0..1023
        int r = idx >> 4;              // k row 0..63
        int c4 = (idx & 15) * 4;
        float4 v = *reinterpret_cast<const float4*>(&W[(size_t)(k0 + r) * DMODEL + n0 + c4]);
        L[r][c4 + 0] = v.x; L[r][c4 + 1] = v.y; L[r][c4 + 2] = v.z; L[r][c4 + 3] = v.w;
    }
    __syncthreads();
    int rn = tid >> 2;                 // out row (n) 0..63
    int ks = (tid & 3) * 16;           // k segment
#pragma unroll
    for (int g = 0; g < 4; ++g) {
        ushort4 h, l;
        float v0 = L[ks + g * 4 + 0][rn];
        float v1 = L[ks + g * 4 + 1][rn];
        float v2 = L[ks + g * 4 + 2][rn];
        float v3 = L[ks + g * 4 + 3][rn];
        h.x = f2bf(v0); l.x = f2bf(v0 - bf2f(h.x));
        h.y = f2bf(v1); l.y = f2bf(v1 - bf2f(h.y));
        h.z = f2bf(v2); l.z = f2bf(v2 - bf2f(h.z));
        h.w = f2bf(v3); l.w = f2bf(v3 - bf2f(h.w));
        size_t o = (size_t)(n0 + rn) * DMODEL + k0 + ks + g * 4;
        *reinterpret_cast<ushort4*>(&Th[o]) = h;
        *reinterpret_cast<ushort4*>(&Tl[o]) = l;
    }
}

// ---------------------------------------------------------------------------
// Split-bf16 MFMA GEMM: C[M=4096, N=1024] = A @ W + bias
// A hi/lo row-major [m][1024]; B = Wt hi/lo [n][k].
// Tile 128x64(MxN), BK=64, 256 thr = 4 waves (wave w: rows w*32..w*32+31).
// LDS layout: rows of 64 bf16 (128B), granule-XOR swizzle: phys_g = g ^ (row&7).
// Staged via global_load_lds (linear LDS dst, pre-swizzled global src).
// MODE 0: fp32 + bias -> Cf
// MODE 1: RoPE + 1/8 -> hi/lo [m][1024]   (Q)
// MODE 2: RoPE       -> hi/lo [m][1024]   (K)
// MODE 3: plain      -> hi/lo [b,h,d,s]   (V^T)
// ---------------------------------------------------------------------------
template<int MODE>
__global__ __launch_bounds__(256) void k_mgemm(const unsigned short* __restrict__ Ah_g,
                                               const unsigned short* __restrict__ Al_g,
                                               const unsigned short* __restrict__ Bh_g,
                                               const unsigned short* __restrict__ Bl_g,
                                               const float* __restrict__ bias,
                                               float* __restrict__ Cf,
                                               unsigned short* __restrict__ Ohi,
                                               unsigned short* __restrict__ Olo,
                                               const float* __restrict__ sin_t,
                                               const float* __restrict__ cos_t) {
    __shared__ unsigned short Ah[128 * 64];
    __shared__ unsigned short Al[128 * 64];
    __shared__ unsigned short Bh[64 * 64];
    __shared__ unsigned short Bl[64 * 64];
    const int tid = threadIdx.x;
    const int lane = tid & 63;
    const int w = tid >> 6;

    // XCD-chunked swizzle: 512 blocks -> 8 chunks of 64 (same-A-stripe grouped)
    int bid = blockIdx.x;
    int wg = (bid & 7) * 64 + (bid >> 3);
    const int m0 = (wg >> 4) * 128;
    const int n0 = (wg & 15) * 64;

    // staging descriptors (element offsets at k0=0); LDS dst wave-uniform
    size_t a_goff[4]; int a_ldst[4];
#pragma unroll
    for (int it = 0; it < 4; ++it) {
        int off = it * 4096 + w * 1024 + lane * 16;   // byte in 16KB tile
        int row = off >> 7;
        int pg = (off >> 4) & 7;
        int lg = pg ^ (row & 7);
        a_goff[it] = (size_t)(m0 + row) * DMODEL + lg * 8;
        a_ldst[it] = it * 2048 + w * 512;             // ushort index
    }
    size_t b_goff[2]; int b_ldst[2];
#pragma unroll
    for (int it = 0; it < 2; ++it) {
        int off = it * 4096 + w * 1024 + lane * 16;
        int row = off >> 7;                            // 0..63
        int pg = (off >> 4) & 7;
        int lg = pg ^ (row & 7);
        b_goff[it] = (size_t)(n0 + row) * DMODEL + lg * 8;
        b_ldst[it] = it * 2048 + w * 512;
    }

    // fragment read offsets (loop-invariant)
    int aoff[2][2], boff[4][2];
#pragma unroll
    for (int mf = 0; mf < 2; ++mf)
#pragma unroll
        for (int ks = 0; ks < 2; ++ks) {
            int row = w * 32 + mf * 16 + (lane & 15);
            int g = ks * 4 + (lane >> 4);
            aoff[mf][ks] = row * 64 + ((g ^ (row & 7)) * 8);
        }
#pragma unroll
    for (int nf = 0; nf < 4; ++nf)
#pragma unroll
        for (int ks = 0; ks < 2; ++ks) {
            int row = nf * 16 + (lane & 15);
            int g = ks * 4 + (lane >> 4);
            boff[nf][ks] = row * 64 + ((g ^ (row & 7)) * 8);
        }

    f32x4 acc[2][4];
#pragma unroll
    for (int mf = 0; mf < 2; ++mf)
#pragma unroll
        for (int nf = 0; nf < 4; ++nf) acc[mf][nf] = (f32x4){0.f, 0.f, 0.f, 0.f};

    for (int kt = 0; kt < 16; ++kt) {
        const int k0 = kt * 64;
#pragma unroll
        for (int it = 0; it < 4; ++it) {
            gl2lds16(Ah_g + a_goff[it] + k0, &Ah[a_ldst[it]]);
            gl2lds16(Al_g + a_goff[it] + k0, &Al[a_ldst[it]]);
        }
#pragma unroll
        for (int it = 0; it < 2; ++it) {
            gl2lds16(Bh_g + b_goff[it] + k0, &Bh[b_ldst[it]]);
            gl2lds16(Bl_g + b_goff[it] + k0, &Bl[b_ldst[it]]);
        }
        __syncthreads();
#pragma unroll
        for (int ks = 0; ks < 2; ++ks) {
            bf16x8 ah[2], al[2], bh[4], bl[4];
#pragma unroll
            for (int mf = 0; mf < 2; ++mf) {
                ah[mf] = *reinterpret_cast<const bf16x8*>(&Ah[aoff[mf][ks]]);
                al[mf] = *reinterpret_cast<const bf16x8*>(&Al[aoff[mf][ks]]);
            }
#pragma unroll
            for (int nf = 0; nf < 4; ++nf) {
                bh[nf] = *reinterpret_cast<const bf16x8*>(&Bh[boff[nf][ks]]);
                bl[nf] = *reinterpret_cast<const bf16x8*>(&Bl[boff[nf][ks]]);
            }
#pragma unroll
            for (int mf = 0; mf < 2; ++mf)
#pragma unroll
                for (int nf = 0; nf < 4; ++nf) {
                    acc[mf][nf] = __builtin_amdgcn_mfma_f32_16x16x32_bf16(al[mf], bh[nf], acc[mf][nf], 0, 0, 0);
                    acc[mf][nf] = __builtin_amdgcn_mfma_f32_16x16x32_bf16(ah[mf], bl[nf], acc[mf][nf], 0, 0, 0);
                    acc[mf][nf] = __builtin_amdgcn_mfma_f32_16x16x32_bf16(ah[mf], bh[nf], acc[mf][nf], 0, 0, 0);
                }
        }
        __syncthreads();
    }

    // epilogue
    const int c = lane & 15;
    const int rq = lane >> 4;
    float bv[4];
#pragma unroll
    for (int nf = 0; nf < 4; ++nf) bv[nf] = bias[n0 + nf * 16 + c];

#pragma unroll
    for (int mf = 0; mf < 2; ++mf) {
        int mbase = m0 + w * 32 + mf * 16 + rq * 4;
        if (MODE == 0) {
#pragma unroll
            for (int nf = 0; nf < 4; ++nf)
#pragma unroll
                for (int r = 0; r < 4; ++r)
                    Cf[(size_t)(mbase + r) * DMODEL + n0 + nf * 16 + c] = acc[mf][nf][r] + bv[nf];
        } else if (MODE == 1 || MODE == 2) {
#pragma unroll
            for (int r = 0; r < 4; ++r) {
                int m = mbase + r;
                int srow = m & (SEQ - 1);
                float x0 = acc[mf][0][r] + bv[0];
                float x1 = acc[mf][1][r] + bv[1];
                float x2 = acc[mf][2][r] + bv[2];
                float x3 = acc[mf][3][r] + bv[3];
                float s0 = sin_t[srow * 32 + c],      c0 = cos_t[srow * 32 + c];
                float s1 = sin_t[srow * 32 + 16 + c], c1 = cos_t[srow * 32 + 16 + c];
                float o0 = c0 * x0 - s0 * x2;
                float o2 = s0 * x0 + c0 * x2;
                float o1 = c1 * x1 - s1 * x3;
                float o3 = s1 * x1 + c1 * x3;
                if (MODE == 1) { o0 *= 0.125f; o1 *= 0.125f; o2 *= 0.125f; o3 *= 0.125f; }
                float ov[4] = { o0, o1, o2, o3 };
                size_t base = (size_t)m * DMODEL + n0 + c;
#pragma unroll
                for (int nf = 0; nf < 4; ++nf) {
                    unsigned short h = f2bf(ov[nf]);
                    Ohi[base + nf * 16] = h;
                    Olo[base + nf * 16] = f2bf(ov[nf] - bf2f(h));
                }
            }
        } else {   // MODE 3: V^T [b,h,d,s]
            int bb = mbase >> 11;
            int s = mbase & (SEQ - 1);
            int h = n0 >> 6;
#pragma unroll
            for (int nf = 0; nf < 4; ++nf) {
                ushort4 h4, l4;
                float v0 = acc[mf][nf][0] + bv[nf];
                float v1 = acc[mf][nf][1] + bv[nf];
                float v2 = acc[mf][nf][2] + bv[nf];
                float v3 = acc[mf][nf][3] + bv[nf];
                h4.x = f2bf(v0); l4.x = f2bf(v0 - bf2f(h4.x));
                h4.y = f2bf(v1); l4.y = f2bf(v1 - bf2f(h4.y));
                h4.z = f2bf(v2); l4.z = f2bf(v2 - bf2f(h4.z));
                h4.w = f2bf(v3); l4.w = f2bf(v3 - bf2f(h4.w));
                int d = nf * 16 + c;
                size_t o = ((size_t)((bb * NH + h) * KD + d)) * SEQ + s;
                *reinterpret_cast<ushort4*>(&Ohi[o]) = h4;
                *reinterpret_cast<ushort4*>(&Olo[o]) = l4;
            }
        }
    }
}

// ---------------------------------------------------------------------------
// Flash attention, bf16-split MFMA (unchanged core; epilogue now emits hi/lo)
// ---------------------------------------------------------------------------
__global__ __launch_bounds__(256) void k_attn(const unsigned short* __restrict__ qhi,
                                              const unsigned short* __restrict__ qlo,
                                              const unsigned short* __restrict__ khi,
                                              const unsigned short* __restrict__ klo,
                                              const unsigned short* __restrict__ vthi,
                                              const unsigned short* __restrict__ vtlo,
                                              unsigned short* __restrict__ ch,
                                              unsigned short* __restrict__ cl) {
    __shared__ unsigned short Kh[64 * 64];
    __shared__ unsigned short Kl[64 * 64];
    __shared__ unsigned short Vh[64 * 64];   // [d][t]
    __shared__ unsigned short Vl[64 * 64];
    __shared__ unsigned short Ps[4][16 * 64];

    const int tid  = threadIdx.x;
    const int lane = tid & 63;
    const int w    = tid >> 6;

    int bid = blockIdx.x;
    int wg  = (bid & 7) * 128 + (bid >> 3);
    const int qt = wg & 31;
    const int h  = (wg >> 5) & 15;
    const int b  = wg >> 9;
    const int q0 = qt * 64;

    bf16x8 qh[2], ql[2];
    {
        size_t qbase = ((size_t)(b * SEQ + q0 + w * 16 + (lane & 15)) * NH + h) * KD
                       + ((lane >> 4) * 8);
        qh[0] = *reinterpret_cast<const bf16x8*>(qhi + qbase);
        qh[1] = *reinterpret_cast<const bf16x8*>(qhi + qbase + 32);
        ql[0] = *reinterpret_cast<const bf16x8*>(qlo + qbase);
        ql[1] = *reinterpret_cast<const bf16x8*>(qlo + qbase + 32);
    }

    f32x4 ctxa[4];
    float m_r[4], l_r[4];
#pragma unroll
    for (int nf = 0; nf < 4; ++nf) ctxa[nf] = (f32x4){0.f, 0.f, 0.f, 0.f};
#pragma unroll
    for (int r = 0; r < 4; ++r) { m_r[r] = -1e30f; l_r[r] = 0.f; }

    for (int t0 = 0; t0 < SEQ; t0 += 64) {
#pragma unroll
        for (int it = 0; it < 2; ++it) {
            int idx = tid + it * 256;
            int row = idx >> 3;
            int c8  = (idx & 7) * 8;
            int sw  = c8 ^ ((row & 7) << 3);
            size_t gk = ((size_t)(b * SEQ + t0 + row) * NH + h) * KD + c8;
            *reinterpret_cast<bf16x8*>(&Kh[row * 64 + sw]) =
                *reinterpret_cast<const bf16x8*>(khi + gk);
            *reinterpret_cast<bf16x8*>(&Kl[row * 64 + sw]) =
                *reinterpret_cast<const bf16x8*>(klo + gk);
            size_t gv = ((size_t)((b * NH + h) * KD + row)) * SEQ + t0 + c8;
            *reinterpret_cast<bf16x8*>(&Vh[row * 64 + sw]) =
                *reinterpret_cast<const bf16x8*>(vthi + gv);
            *reinterpret_cast<bf16x8*>(&Vl[row * 64 + sw]) =
                *reinterpret_cast<const bf16x8*>(vtlo + gv);
        }
        __syncthreads();

        f32x4 s[4];
#pragma unroll
        for (int nf = 0; nf < 4; ++nf) s[nf] = (f32x4){0.f, 0.f, 0.f, 0.f};
#pragma unroll
        for (int nf = 0; nf < 4; ++nf) {
#pragma unroll
            for (int ks = 0; ks < 2; ++ks) {
                int trow = nf * 16 + (lane & 15);
                int koff = trow * 64 + ((ks * 32 + (lane >> 4) * 8) ^ ((trow & 7) << 3));
                bf16x8 kh = *reinterpret_cast<const bf16x8*>(&Kh[koff]);
                bf16x8 kl = *reinterpret_cast<const bf16x8*>(&Kl[koff]);
                s[nf] = __builtin_amdgcn_mfma_f32_16x16x32_bf16(ql[ks], kh, s[nf], 0, 0, 0);
                s[nf] = __builtin_amdgcn_mfma_f32_16x16x32_bf16(qh[ks], kl, s[nf], 0, 0, 0);
                s[nf] = __builtin_amdgcn_mfma_f32_16x16x32_bf16(qh[ks], kh, s[nf], 0, 0, 0);
            }
        }

        float alpha[4];
#pragma unroll
        for (int r = 0; r < 4; ++r) {
            float rm = fmaxf(fmaxf(s[0][r], s[1][r]), fmaxf(s[2][r], s[3][r]));
            rm = fmaxf(rm, __shfl_xor(rm, 1));
            rm = fmaxf(rm, __shfl_xor(rm, 2));
            rm = fmaxf(rm, __shfl_xor(rm, 4));
            rm = fmaxf(rm, __shfl_xor(rm, 8));
            float mn = fmaxf(m_r[r], rm);
            float al = __expf(m_r[r] - mn);
            float rs = 0.f;
            int qloc = (lane >> 4) * 4 + r;
#pragma unroll
            for (int nf = 0; nf < 4; ++nf) {
                float p = __expf(s[nf][r] - mn);
                rs += p;
                int t = nf * 16 + (lane & 15);
                Ps[w][qloc * 64 + (t ^ ((qloc & 7) << 3))] = f2bf(p);
            }
            rs += __shfl_xor(rs, 1);
            rs += __shfl_xor(rs, 2);
            rs += __shfl_xor(rs, 4);
            rs += __shfl_xor(rs, 8);
            m_r[r] = mn;
            l_r[r] = l_r[r] * al + rs;
            alpha[r] = al;
        }
#pragma unroll
        for (int nf = 0; nf < 4; ++nf)
#pragma unroll
            for (int r = 0; r < 4; ++r) ctxa[nf][r] *= alpha[r];

#pragma unroll
        for (int ks = 0; ks < 2; ++ks) {
            int qrow = lane & 15;
            int aoff = qrow * 64 + ((ks * 32 + (lane >> 4) * 8) ^ ((qrow & 7) << 3));
            bf16x8 pa = *reinterpret_cast<const bf16x8*>(&Ps[w][aoff]);
#pragma unroll
            for (int nf = 0; nf < 4; ++nf) {
                int drow = nf * 16 + (lane & 15);
                int voff = drow * 64 + ((ks * 32 + (lane >> 4) * 8) ^ ((drow & 7) << 3));
                bf16x8 vh = *reinterpret_cast<const bf16x8*>(&Vh[voff]);
                bf16x8 vl = *reinterpret_cast<const bf16x8*>(&Vl[voff]);
                ctxa[nf] = __builtin_amdgcn_mfma_f32_16x16x32_bf16(pa, vh, ctxa[nf], 0, 0, 0);
                ctxa[nf] = __builtin_amdgcn_mfma_f32_16x16x32_bf16(pa, vl, ctxa[nf], 0, 0, 0);
            }
        }
        __syncthreads();
    }

#pragma unroll
    for (int nf = 0; nf < 4; ++nf) {
#pragma unroll
        for (int r = 0; r < 4; ++r) {
            int qloc = (lane >> 4) * 4 + r;
            int qg = q0 + w * 16 + qloc;
            int d = nf * 16 + (lane & 15);
            float val = ctxa[nf][r] / l_r[r];
            size_t o = ((size_t)(b * SEQ + qg) * NH + h) * KD + d;
            unsigned short hv = f2bf(val);
            ch[o] = hv;
            cl[o] = f2bf(val - bf2f(hv));
        }
    }
}

// ---------------------------------------------------------------------------
extern "C" void kernel_launch(void* const* d_in, const int* in_sizes, int n_in,
                              void* d_out, int out_size, void* d_ws, size_t ws_size,
                              hipStream_t stream) {
    const float* x  = (const float*)d_in[0];
    const float* Wq = (const float*)d_in[1];
    const float* bq = (const float*)d_in[2];
    const float* Wk = (const float*)d_in[3];
    const float* bk = (const float*)d_in[4];
    const float* Wv = (const float*)d_in[5];
    const float* bv = (const float*)d_in[6];
    const float* Wo = (const float*)d_in[7];
    const float* bo = (const float*)d_in[8];
    float* out = (float*)d_out;

    const size_t NE = (size_t)MROWS * DMODEL;   // 4M
    const size_t WE = (size_t)DMODEL * DMODEL;  // 1M
    float* ws    = (float*)d_ws;
    float* sin_t = ws;
    float* cos_t = sin_t + SEQ * 32;
    unsigned short* p = (unsigned short*)(cos_t + SEQ * 32);
    unsigned short* xh   = p; p += NE;
    unsigned short* xl   = p; p += NE;
    unsigned short* qhi  = p; p += NE;
    unsigned short* qlo  = p; p += NE;
    unsigned short* khi_ = p; p += NE;
    unsigned short* klo_ = p; p += NE;
    unsigned short* vthi = p; p += NE;
    unsigned short* vtlo = p; p += NE;
    unsigned short* wqh = p; p += WE;
    unsigned short* wql = p; p += WE;
    unsigned short* wkh = p; p += WE;
    unsigned short* wkl = p; p += WE;
    unsigned short* wvh = p; p += WE;
    unsigned short* wvl = p; p += WE;
    unsigned short* woh = p; p += WE;
    unsigned short* wol = p; p += WE;
    // ctx hi/lo alias x hi/lo (x dead after V projection)
    unsigned short* ctxh = xh;
    unsigned short* ctxl = xl;

    k_rope_tables<<<(SEQ * 32 + 255) / 256, 256, 0, stream>>>(sin_t, cos_t);
    k_cvt_x<<<(int)(NE / 4 / 256), 256, 0, stream>>>(x, xh, xl);
    dim3 tg(16, 16);
    k_cvt_wT<<<tg, 256, 0, stream>>>(Wq, wqh, wql);
    k_cvt_wT<<<tg, 256, 0, stream>>>(Wk, wkh, wkl);
    k_cvt_wT<<<tg, 256, 0, stream>>>(Wv, wvh, wvl);
    k_cvt_wT<<<tg, 256, 0, stream>>>(Wo, woh, wol);

    k_mgemm<1><<<512, 256, 0, stream>>>(xh, xl, wqh, wql, bq, nullptr, qhi, qlo, sin_t, cos_t);
    k_mgemm<2><<<512, 256, 0, stream>>>(xh, xl, wkh, wkl, bk, nullptr, khi_, klo_, sin_t, cos_t);
    k_mgemm<3><<<512, 256, 0, stream>>>(xh, xl, wvh, wvl, bv, nullptr, vthi, vtlo, nullptr, nullptr);

    k_attn<<<BATCH * NH * (SEQ / 64), 256, 0, stream>>>(qhi, qlo, khi_, klo_, vthi, vtlo, ctxh, ctxl);

    k_mgemm<0><<<512, 256, 0, stream>>>(ctxh, ctxl, woh, wol, bo, out, nullptr, nullptr, nullptr, nullptr);
}

// Round 5
// 258.149 us; speedup vs baseline: 5.1922x; 1.1623x over previous
//
#include <hip/hip_runtime.h>
#include <math.h>

#define NH 16
#define KD 64
#define DMODEL 1024
#define BATCH 2
#define SEQ 2048
#define MROWS (BATCH*SEQ)

typedef float f32x4 __attribute__((ext_vector_type(4)));
typedef __bf16 bf16x8 __attribute__((ext_vector_type(8)));

__device__ __forceinline__ unsigned short f2bf(float x) {
    union { float f; unsigned u; } a; a.f = x;
    unsigned r = a.u + 0x7fffu + ((a.u >> 16) & 1u);
    return (unsigned short)(r >> 16);
}
__device__ __forceinline__ float bf2f(unsigned short h) {
    union { unsigned u; float f; } a; a.u = ((unsigned)h) << 16; return a.f;
}

__device__ __forceinline__ void gl2lds16(const void* gsrc, void* ldst) {
    __builtin_amdgcn_global_load_lds(
        (const __attribute__((address_space(1))) void*)gsrc,
        (__attribute__((address_space(3))) void*)ldst, 16, 0, 0);
}

// ---------------------------------------------------------------------------
__global__ __launch_bounds__(256) void k_rope_tables(float* __restrict__ sin_t,
                                                     float* __restrict__ cos_t) {
    int idx = blockIdx.x * 256 + threadIdx.x;
    if (idx >= SEQ * 32) return;
    int s = idx >> 5, i = idx & 31;
    float invf = expf((float)(2 * i) * (-logf(10000.0f) / (float)KD));
    float ang = (float)s * invf;
    sin_t[idx] = sinf(ang);
    cos_t[idx] = cosf(ang);
}

// ---------------------------------------------------------------------------
__global__ __launch_bounds__(256) void k_cvt_x(const float* __restrict__ x,
                                               unsigned short* __restrict__ xh,
                                               unsigned short* __restrict__ xl) {
    int idx = blockIdx.x * 256 + threadIdx.x;
    float4 v = reinterpret_cast<const float4*>(x)[idx];
    ushort4 h, l;
    h.x = f2bf(v.x); l.x = f2bf(v.x - bf2f(h.x));
    h.y = f2bf(v.y); l.y = f2bf(v.y - bf2f(h.y));
    h.z = f2bf(v.z); l.z = f2bf(v.z - bf2f(h.z));
    h.w = f2bf(v.w); l.w = f2bf(v.w - bf2f(h.w));
    reinterpret_cast<ushort4*>(xh)[idx] = h;
    reinterpret_cast<ushort4*>(xl)[idx] = l;
}

// ---------------------------------------------------------------------------
__global__ __launch_bounds__(256) void k_cvt_wT(const float* __restrict__ W,
                                                unsigned short* __restrict__ Th,
                                                unsigned short* __restrict__ Tl) {
    __shared__ float L[64][65];
    const int tid = threadIdx.x;
    const int n0 = blockIdx.x * 64, k0 = blockIdx.y * 64;
#pragma unroll
    for (int it = 0; it < 4; ++it) {
        int idx = tid + it * 256;
        int r = idx >> 4;
        int c4 = (idx & 15) * 4;
        float4 v = *reinterpret_cast<const float4*>(&W[(size_t)(k0 + r) * DMODEL + n0 + c4]);
        L[r][c4 + 0] = v.x; L[r][c4 + 1] = v.y; L[r][c4 + 2] = v.z; L[r][c4 + 3] = v.w;
    }
    __syncthreads();
    int rn = tid >> 2;
    int ks = (tid & 3) * 16;
#pragma unroll
    for (int g = 0; g < 4; ++g) {
        ushort4 h, l;
        float v0 = L[ks + g * 4 + 0][rn];
        float v1 = L[ks + g * 4 + 1][rn];
        float v2 = L[ks + g * 4 + 2][rn];
        float v3 = L[ks + g * 4 + 3][rn];
        h.x = f2bf(v0); l.x = f2bf(v0 - bf2f(h.x));
        h.y = f2bf(v1); l.y = f2bf(v1 - bf2f(h.y));
        h.z = f2bf(v2); l.z = f2bf(v2 - bf2f(h.z));
        h.w = f2bf(v3); l.w = f2bf(v3 - bf2f(h.w));
        size_t o = (size_t)(n0 + rn) * DMODEL + k0 + ks + g * 4;
        *reinterpret_cast<ushort4*>(&Th[o]) = h;
        *reinterpret_cast<ushort4*>(&Tl[o]) = l;
    }
}

// ---------------------------------------------------------------------------
// Split-bf16 MFMA GEMM (3-MFMA). Tile 128x64, BK=64, 4 waves.
// MODE 0: fp32+bias -> Cf; MODE 1: RoPE+1/8 -> bf16 hi (Q);
// MODE 2: RoPE -> bf16 hi (K); MODE 3: plain -> bf16 hi [b,h,d,s] (V^T).
// WLO: also write lo split (used only for ctx path via attn, not here).
// ---------------------------------------------------------------------------
template<int MODE, bool WLO>
__global__ __launch_bounds__(256) void k_mgemm(const unsigned short* __restrict__ Ah_g,
                                               const unsigned short* __restrict__ Al_g,
                                               const unsigned short* __restrict__ Bh_g,
                                               const unsigned short* __restrict__ Bl_g,
                                               const float* __restrict__ bias,
                                               float* __restrict__ Cf,
                                               unsigned short* __restrict__ Ohi,
                                               unsigned short* __restrict__ Olo,
                                               const float* __restrict__ sin_t,
                                               const float* __restrict__ cos_t) {
    __shared__ unsigned short Ah[128 * 64];
    __shared__ unsigned short Al[128 * 64];
    __shared__ unsigned short Bh[64 * 64];
    __shared__ unsigned short Bl[64 * 64];
    const int tid = threadIdx.x;
    const int lane = tid & 63;
    const int w = tid >> 6;

    int bid = blockIdx.x;
    int wg = (bid & 7) * 64 + (bid >> 3);
    const int m0 = (wg >> 4) * 128;
    const int n0 = (wg & 15) * 64;

    size_t a_goff[4]; int a_ldst[4];
#pragma unroll
    for (int it = 0; it < 4; ++it) {
        int off = it * 4096 + w * 1024 + lane * 16;
        int row = off >> 7;
        int pg = (off >> 4) & 7;
        int lg = pg ^ (row & 7);
        a_goff[it] = (size_t)(m0 + row) * DMODEL + lg * 8;
        a_ldst[it] = it * 2048 + w * 512;
    }
    size_t b_goff[2]; int b_ldst[2];
#pragma unroll
    for (int it = 0; it < 2; ++it) {
        int off = it * 4096 + w * 1024 + lane * 16;
        int row = off >> 7;
        int pg = (off >> 4) & 7;
        int lg = pg ^ (row & 7);
        b_goff[it] = (size_t)(n0 + row) * DMODEL + lg * 8;
        b_ldst[it] = it * 2048 + w * 512;
    }

    int aoff[2][2], boff[4][2];
#pragma unroll
    for (int mf = 0; mf < 2; ++mf)
#pragma unroll
        for (int ks = 0; ks < 2; ++ks) {
            int row = w * 32 + mf * 16 + (lane & 15);
            int g = ks * 4 + (lane >> 4);
            aoff[mf][ks] = row * 64 + ((g ^ (row & 7)) * 8);
        }
#pragma unroll
    for (int nf = 0; nf < 4; ++nf)
#pragma unroll
        for (int ks = 0; ks < 2; ++ks) {
            int row = nf * 16 + (lane & 15);
            int g = ks * 4 + (lane >> 4);
            boff[nf][ks] = row * 64 + ((g ^ (row & 7)) * 8);
        }

    f32x4 acc[2][4];
#pragma unroll
    for (int mf = 0; mf < 2; ++mf)
#pragma unroll
        for (int nf = 0; nf < 4; ++nf) acc[mf][nf] = (f32x4){0.f, 0.f, 0.f, 0.f};

    for (int kt = 0; kt < 16; ++kt) {
        const int k0 = kt * 64;
#pragma unroll
        for (int it = 0; it < 4; ++it) {
            gl2lds16(Ah_g + a_goff[it] + k0, &Ah[a_ldst[it]]);
            gl2lds16(Al_g + a_goff[it] + k0, &Al[a_ldst[it]]);
        }
#pragma unroll
        for (int it = 0; it < 2; ++it) {
            gl2lds16(Bh_g + b_goff[it] + k0, &Bh[b_ldst[it]]);
            gl2lds16(Bl_g + b_goff[it] + k0, &Bl[b_ldst[it]]);
        }
        __syncthreads();
#pragma unroll
        for (int ks = 0; ks < 2; ++ks) {
            bf16x8 ah[2], al[2], bh[4], bl[4];
#pragma unroll
            for (int mf = 0; mf < 2; ++mf) {
                ah[mf] = *reinterpret_cast<const bf16x8*>(&Ah[aoff[mf][ks]]);
                al[mf] = *reinterpret_cast<const bf16x8*>(&Al[aoff[mf][ks]]);
            }
#pragma unroll
            for (int nf = 0; nf < 4; ++nf) {
                bh[nf] = *reinterpret_cast<const bf16x8*>(&Bh[boff[nf][ks]]);
                bl[nf] = *reinterpret_cast<const bf16x8*>(&Bl[boff[nf][ks]]);
            }
#pragma unroll
            for (int mf = 0; mf < 2; ++mf)
#pragma unroll
                for (int nf = 0; nf < 4; ++nf) {
                    acc[mf][nf] = __builtin_amdgcn_mfma_f32_16x16x32_bf16(al[mf], bh[nf], acc[mf][nf], 0, 0, 0);
                    acc[mf][nf] = __builtin_amdgcn_mfma_f32_16x16x32_bf16(ah[mf], bl[nf], acc[mf][nf], 0, 0, 0);
                    acc[mf][nf] = __builtin_amdgcn_mfma_f32_16x16x32_bf16(ah[mf], bh[nf], acc[mf][nf], 0, 0, 0);
                }
        }
        __syncthreads();
    }

    const int c = lane & 15;
    const int rq = lane >> 4;
    float bv[4];
#pragma unroll
    for (int nf = 0; nf < 4; ++nf) bv[nf] = bias[n0 + nf * 16 + c];

#pragma unroll
    for (int mf = 0; mf < 2; ++mf) {
        int mbase = m0 + w * 32 + mf * 16 + rq * 4;
        if (MODE == 0) {
#pragma unroll
            for (int nf = 0; nf < 4; ++nf)
#pragma unroll
                for (int r = 0; r < 4; ++r)
                    Cf[(size_t)(mbase + r) * DMODEL + n0 + nf * 16 + c] = acc[mf][nf][r] + bv[nf];
        } else if (MODE == 1 || MODE == 2) {
#pragma unroll
            for (int r = 0; r < 4; ++r) {
                int m = mbase + r;
                int srow = m & (SEQ - 1);
                float x0 = acc[mf][0][r] + bv[0];
                float x1 = acc[mf][1][r] + bv[1];
                float x2 = acc[mf][2][r] + bv[2];
                float x3 = acc[mf][3][r] + bv[3];
                float s0 = sin_t[srow * 32 + c],      c0 = cos_t[srow * 32 + c];
                float s1 = sin_t[srow * 32 + 16 + c], c1 = cos_t[srow * 32 + 16 + c];
                float o0 = c0 * x0 - s0 * x2;
                float o2 = s0 * x0 + c0 * x2;
                float o1 = c1 * x1 - s1 * x3;
                float o3 = s1 * x1 + c1 * x3;
                if (MODE == 1) { o0 *= 0.125f; o1 *= 0.125f; o2 *= 0.125f; o3 *= 0.125f; }
                float ov[4] = { o0, o1, o2, o3 };
                size_t base = (size_t)m * DMODEL + n0 + c;
#pragma unroll
                for (int nf = 0; nf < 4; ++nf) {
                    unsigned short h = f2bf(ov[nf]);
                    Ohi[base + nf * 16] = h;
                    if (WLO) Olo[base + nf * 16] = f2bf(ov[nf] - bf2f(h));
                }
            }
        } else {   // MODE 3: V^T [b,h,d,s] hi only
            int bb = mbase >> 11;
            int s = mbase & (SEQ - 1);
            int h = n0 >> 6;
#pragma unroll
            for (int nf = 0; nf < 4; ++nf) {
                ushort4 h4;
                float v0 = acc[mf][nf][0] + bv[nf];
                float v1 = acc[mf][nf][1] + bv[nf];
                float v2 = acc[mf][nf][2] + bv[nf];
                float v3 = acc[mf][nf][3] + bv[nf];
                h4.x = f2bf(v0); h4.y = f2bf(v1); h4.z = f2bf(v2); h4.w = f2bf(v3);
                int d = nf * 16 + c;
                size_t o = ((size_t)((bb * NH + h) * KD + d)) * SEQ + s;
                *reinterpret_cast<ushort4*>(&Ohi[o]) = h4;
            }
        }
    }
}

// ---------------------------------------------------------------------------
// Flash attention, plain bf16 MFMA. Block = 256 thr (4 waves), 128 q-rows;
// wave owns 32 rows (2 m-frags). KV tiles of 64, double-buffered async
// staging (global_load_lds, pre-swizzled source), raw s_barrier + vmcnt(4).
// ---------------------------------------------------------------------------
__global__ __launch_bounds__(256) void k_attn(const unsigned short* __restrict__ qhi,
                                              const unsigned short* __restrict__ khi,
                                              const unsigned short* __restrict__ vthi,
                                              unsigned short* __restrict__ ch,
                                              unsigned short* __restrict__ cl) {
    __shared__ unsigned short Kh[2][64 * 64];
    __shared__ unsigned short Vh[2][64 * 64];   // [d][t]
    __shared__ unsigned short Ps[4][32 * 64];

    const int tid  = threadIdx.x;
    const int lane = tid & 63;
    const int w    = tid >> 6;

    // 512 blocks -> 8 XCD chunks of 64 (4 heads' K/V per chunk ~ 2MB, L2-fits)
    int bid = blockIdx.x;
    int wg  = (bid & 7) * 64 + (bid >> 3);
    const int qt = wg & 15;
    const int h  = (wg >> 4) & 15;
    const int b  = wg >> 8;
    const int q0 = qt * 128;

    // Q fragments (plain bf16, pre-scaled 1/8)
    bf16x8 qf[2][2];   // [mf][ks]
#pragma unroll
    for (int mf = 0; mf < 2; ++mf)
#pragma unroll
        for (int ks = 0; ks < 2; ++ks) {
            int row = q0 + w * 32 + mf * 16 + (lane & 15);
            int d = ks * 32 + (lane >> 4) * 8;
            qf[mf][ks] = *reinterpret_cast<const bf16x8*>(
                qhi + ((size_t)(b * SEQ + row) * NH + h) * KD + d);
        }

    // staging addresses (pre-swizzled global source, linear LDS dest)
    size_t gK[2], gV[2]; int ld_[2];
#pragma unroll
    for (int it = 0; it < 2; ++it) {
        int off = it * 4096 + tid * 16;     // byte in 8KB tile
        int row = off >> 7;                 // 0..63
        int pg = (off >> 4) & 7;
        int lg = pg ^ (row & 7);
        gK[it] = ((size_t)(b * SEQ + row) * NH + h) * KD + lg * 8;
        gV[it] = ((size_t)(b * NH + h) * KD + row) * SEQ + lg * 8;
        ld_[it] = it * 2048 + w * 512;      // ushort idx, wave-uniform
    }

    f32x4 acc[2][4];
    float m_r[2][4], l_r[2][4];
#pragma unroll
    for (int mf = 0; mf < 2; ++mf) {
#pragma unroll
        for (int nf = 0; nf < 4; ++nf) acc[mf][nf] = (f32x4){0.f, 0.f, 0.f, 0.f};
#pragma unroll
        for (int r = 0; r < 4; ++r) { m_r[mf][r] = -1e30f; l_r[mf][r] = 0.f; }
    }

#define STAGE(BUF, TT) do {                                                  \
        size_t kadv = (size_t)(TT) * 64 * NH * KD;                           \
        size_t vadv = (size_t)(TT) * 64;                                     \
        gl2lds16(khi  + gK[0] + kadv, &Kh[BUF][ld_[0]]);                     \
        gl2lds16(khi  + gK[1] + kadv, &Kh[BUF][ld_[1]]);                     \
        gl2lds16(vthi + gV[0] + vadv, &Vh[BUF][ld_[0]]);                     \
        gl2lds16(vthi + gV[1] + vadv, &Vh[BUF][ld_[1]]);                     \
    } while (0)

    STAGE(0, 0);

    for (int t = 0; t < 32; ++t) {
        const int cur = t & 1;
        if (t < 31) {
            STAGE(cur ^ 1, t + 1);
            asm volatile("s_waitcnt vmcnt(4)" ::: "memory");
        } else {
            asm volatile("s_waitcnt vmcnt(0)" ::: "memory");
        }
        __builtin_amdgcn_s_barrier();

        // ---- QK^T ----
        f32x4 s[2][4];
#pragma unroll
        for (int mf = 0; mf < 2; ++mf)
#pragma unroll
            for (int nf = 0; nf < 4; ++nf) s[mf][nf] = (f32x4){0.f, 0.f, 0.f, 0.f};
#pragma unroll
        for (int nf = 0; nf < 4; ++nf) {
#pragma unroll
            for (int ks = 0; ks < 2; ++ks) {
                int trow = nf * 16 + (lane & 15);
                int koff = trow * 64 + (((ks * 4 + (lane >> 4)) ^ (trow & 7)) * 8);
                bf16x8 kf = *reinterpret_cast<const bf16x8*>(&Kh[cur][koff]);
#pragma unroll
                for (int mf = 0; mf < 2; ++mf)
                    s[mf][nf] = __builtin_amdgcn_mfma_f32_16x16x32_bf16(qf[mf][ks], kf, s[mf][nf], 0, 0, 0);
            }
        }

        // ---- online softmax ----
#pragma unroll
        for (int mf = 0; mf < 2; ++mf) {
            float alpha[4];
#pragma unroll
            for (int r = 0; r < 4; ++r) {
                float rm = fmaxf(fmaxf(s[mf][0][r], s[mf][1][r]),
                                 fmaxf(s[mf][2][r], s[mf][3][r]));
                rm = fmaxf(rm, __shfl_xor(rm, 1));
                rm = fmaxf(rm, __shfl_xor(rm, 2));
                rm = fmaxf(rm, __shfl_xor(rm, 4));
                rm = fmaxf(rm, __shfl_xor(rm, 8));
                float mn = fmaxf(m_r[mf][r], rm);
                float al = __expf(m_r[mf][r] - mn);
                float rs = 0.f;
                int qloc = mf * 16 + (lane >> 4) * 4 + r;
#pragma unroll
                for (int nf = 0; nf < 4; ++nf) {
                    float pv = __expf(s[mf][nf][r] - mn);
                    rs += pv;
                    int t_ = nf * 16 + (lane & 15);
                    Ps[w][qloc * 64 + (t_ ^ ((qloc & 7) << 3))] = f2bf(pv);
                }
                rs += __shfl_xor(rs, 1);
                rs += __shfl_xor(rs, 2);
                rs += __shfl_xor(rs, 4);
                rs += __shfl_xor(rs, 8);
                m_r[mf][r] = mn;
                l_r[mf][r] = l_r[mf][r] * al + rs;
                alpha[r] = al;
            }
#pragma unroll
            for (int nf = 0; nf < 4; ++nf)
#pragma unroll
                for (int r = 0; r < 4; ++r) acc[mf][nf][r] *= alpha[r];
        }

        // ---- PV ----
#pragma unroll
        for (int ks = 0; ks < 2; ++ks) {
            bf16x8 pa[2];
#pragma unroll
            for (int mf = 0; mf < 2; ++mf) {
                int row = mf * 16 + (lane & 15);
                int aoff = row * 64 + (((ks * 4 + (lane >> 4)) ^ (row & 7)) * 8);
                pa[mf] = *reinterpret_cast<const bf16x8*>(&Ps[w][aoff]);
            }
#pragma unroll
            for (int nf = 0; nf < 4; ++nf) {
                int drow = nf * 16 + (lane & 15);
                int voff = drow * 64 + (((ks * 4 + (lane >> 4)) ^ (drow & 7)) * 8);
                bf16x8 vf = *reinterpret_cast<const bf16x8*>(&Vh[cur][voff]);
#pragma unroll
                for (int mf = 0; mf < 2; ++mf)
                    acc[mf][nf] = __builtin_amdgcn_mfma_f32_16x16x32_bf16(pa[mf], vf, acc[mf][nf], 0, 0, 0);
            }
        }
        __builtin_amdgcn_s_barrier();
    }
#undef STAGE

    // ---- normalize + store ctx bf16 hi/lo [b,s,h,d] ----
#pragma unroll
    for (int mf = 0; mf < 2; ++mf) {
#pragma unroll
        for (int r = 0; r < 4; ++r) {
            float inv = 1.0f / l_r[mf][r];
            int qg = q0 + w * 32 + mf * 16 + (lane >> 4) * 4 + r;
#pragma unroll
            for (int nf = 0; nf < 4; ++nf) {
                int d = nf * 16 + (lane & 15);
                float val = acc[mf][nf][r] * inv;
                size_t o = ((size_t)(b * SEQ + qg) * NH + h) * KD + d;
                unsigned short hv = f2bf(val);
                ch[o] = hv;
                cl[o] = f2bf(val - bf2f(hv));
            }
        }
    }
}

// ---------------------------------------------------------------------------
extern "C" void kernel_launch(void* const* d_in, const int* in_sizes, int n_in,
                              void* d_out, int out_size, void* d_ws, size_t ws_size,
                              hipStream_t stream) {
    const float* x  = (const float*)d_in[0];
    const float* Wq = (const float*)d_in[1];
    const float* bq = (const float*)d_in[2];
    const float* Wk = (const float*)d_in[3];
    const float* bk = (const float*)d_in[4];
    const float* Wv = (const float*)d_in[5];
    const float* bv = (const float*)d_in[6];
    const float* Wo = (const float*)d_in[7];
    const float* bo = (const float*)d_in[8];
    float* out = (float*)d_out;

    const size_t NE = (size_t)MROWS * DMODEL;   // 4M
    const size_t WE = (size_t)DMODEL * DMODEL;  // 1M
    float* ws    = (float*)d_ws;
    float* sin_t = ws;
    float* cos_t = sin_t + SEQ * 32;
    unsigned short* p = (unsigned short*)(cos_t + SEQ * 32);
    unsigned short* xh   = p; p += NE;
    unsigned short* xl   = p; p += NE;
    unsigned short* qh_  = p; p += NE;
    unsigned short* kh_  = p; p += NE;
    unsigned short* vth  = p; p += NE;
    unsigned short* wqh = p; p += WE;
    unsigned short* wql = p; p += WE;
    unsigned short* wkh = p; p += WE;
    unsigned short* wkl = p; p += WE;
    unsigned short* wvh = p; p += WE;
    unsigned short* wvl = p; p += WE;
    unsigned short* woh = p; p += WE;
    unsigned short* wol = p; p += WE;
    // ctx hi/lo alias x hi/lo (x dead after V projection)
    unsigned short* ctxh = xh;
    unsigned short* ctxl = xl;

    k_rope_tables<<<(SEQ * 32 + 255) / 256, 256, 0, stream>>>(sin_t, cos_t);
    k_cvt_x<<<(int)(NE / 4 / 256), 256, 0, stream>>>(x, xh, xl);
    dim3 tg(16, 16);
    k_cvt_wT<<<tg, 256, 0, stream>>>(Wq, wqh, wql);
    k_cvt_wT<<<tg, 256, 0, stream>>>(Wk, wkh, wkl);
    k_cvt_wT<<<tg, 256, 0, stream>>>(Wv, wvh, wvl);
    k_cvt_wT<<<tg, 256, 0, stream>>>(Wo, woh, wol);

    k_mgemm<1, false><<<512, 256, 0, stream>>>(xh, xl, wqh, wql, bq, nullptr, qh_, nullptr, sin_t, cos_t);
    k_mgemm<2, false><<<512, 256, 0, stream>>>(xh, xl, wkh, wkl, bk, nullptr, kh_, nullptr, sin_t, cos_t);
    k_mgemm<3, false><<<512, 256, 0, stream>>>(xh, xl, wvh, wvl, bv, nullptr, vth, nullptr, nullptr, nullptr);

    k_attn<<<512, 256, 0, stream>>>(qh_, kh_, vth, ctxh, ctxl);

    k_mgemm<0, false><<<512, 256, 0, stream>>>(ctxh, ctxl, woh, wol, bo, out, nullptr, nullptr, nullptr, nullptr);
}

// Round 7
// 189.388 us; speedup vs baseline: 7.0773x; 1.3631x over previous
//
#include <hip/hip_runtime.h>
#include <math.h>

#define NH 16
#define KD 64
#define DMODEL 1024
#define BATCH 2
#define SEQ 2048
#define MROWS (BATCH*SEQ)

typedef float f32x4 __attribute__((ext_vector_type(4)));
typedef __bf16 bf16x8 __attribute__((ext_vector_type(8)));

__device__ __forceinline__ unsigned short f2bf(float x) {
    union { float f; unsigned u; } a; a.f = x;
    unsigned r = a.u + 0x7fffu + ((a.u >> 16) & 1u);
    return (unsigned short)(r >> 16);
}
__device__ __forceinline__ float bf2f(unsigned short h) {
    union { unsigned u; float f; } a; a.u = ((unsigned)h) << 16; return a.f;
}
__device__ __forceinline__ unsigned cvt_pk_bf16(float lo, float hi) {
    unsigned r;
    asm("v_cvt_pk_bf16_f32 %0, %1, %2" : "=v"(r) : "v"(lo), "v"(hi));
    return r;
}
// 2^x on the VALU transcendental unit
__device__ __forceinline__ float exp2_hw(float x) {
    float r;
    asm("v_exp_f32 %0, %1" : "=v"(r) : "v"(x));
    return r;
}

__device__ __forceinline__ void gl2lds16(const void* gsrc, void* ldst) {
    __builtin_amdgcn_global_load_lds(
        (const __attribute__((address_space(1))) void*)gsrc,
        (__attribute__((address_space(3))) void*)ldst, 16, 0, 0);
}

// ---------------------------------------------------------------------------
__global__ __launch_bounds__(256) void k_rope_tables(float* __restrict__ sin_t,
                                                     float* __restrict__ cos_t) {
    int idx = blockIdx.x * 256 + threadIdx.x;
    if (idx >= SEQ * 32) return;
    int s = idx >> 5, i = idx & 31;
    float invf = expf((float)(2 * i) * (-logf(10000.0f) / (float)KD));
    float ang = (float)s * invf;
    sin_t[idx] = sinf(ang);
    cos_t[idx] = cosf(ang);
}

// ---------------------------------------------------------------------------
__global__ __launch_bounds__(256) void k_cvt_x(const float* __restrict__ x,
                                               unsigned short* __restrict__ xh,
                                               unsigned short* __restrict__ xl) {
    int idx = blockIdx.x * 256 + threadIdx.x;
    float4 v = reinterpret_cast<const float4*>(x)[idx];
    ushort4 h, l;
    h.x = f2bf(v.x); l.x = f2bf(v.x - bf2f(h.x));
    h.y = f2bf(v.y); l.y = f2bf(v.y - bf2f(h.y));
    h.z = f2bf(v.z); l.z = f2bf(v.z - bf2f(h.z));
    h.w = f2bf(v.w); l.w = f2bf(v.w - bf2f(h.w));
    reinterpret_cast<ushort4*>(xh)[idx] = h;
    reinterpret_cast<ushort4*>(xl)[idx] = l;
}

// ---------------------------------------------------------------------------
__global__ __launch_bounds__(256) void k_cvt_wT(const float* __restrict__ W,
                                                unsigned short* __restrict__ Th,
                                                unsigned short* __restrict__ Tl) {
    __shared__ float L[64][65];
    const int tid = threadIdx.x;
    const int n0 = blockIdx.x * 64, k0 = blockIdx.y * 64;
#pragma unroll
    for (int it = 0; it < 4; ++it) {
        int idx = tid + it * 256;
        int r = idx >> 4;
        int c4 = (idx & 15) * 4;
        float4 v = *reinterpret_cast<const float4*>(&W[(size_t)(k0 + r) * DMODEL + n0 + c4]);
        L[r][c4 + 0] = v.x; L[r][c4 + 1] = v.y; L[r][c4 + 2] = v.z; L[r][c4 + 3] = v.w;
    }
    __syncthreads();
    int rn = tid >> 2;
    int ks = (tid & 3) * 16;
#pragma unroll
    for (int g = 0; g < 4; ++g) {
        ushort4 h, l;
        float v0 = L[ks + g * 4 + 0][rn];
        float v1 = L[ks + g * 4 + 1][rn];
        float v2 = L[ks + g * 4 + 2][rn];
        float v3 = L[ks + g * 4 + 3][rn];
        h.x = f2bf(v0); l.x = f2bf(v0 - bf2f(h.x));
        h.y = f2bf(v1); l.y = f2bf(v1 - bf2f(h.y));
        h.z = f2bf(v2); l.z = f2bf(v2 - bf2f(h.z));
        h.w = f2bf(v3); l.w = f2bf(v3 - bf2f(h.w));
        size_t o = (size_t)(n0 + rn) * DMODEL + k0 + ks + g * 4;
        *reinterpret_cast<ushort4*>(&Th[o]) = h;
        *reinterpret_cast<ushort4*>(&Tl[o]) = l;
    }
}

// ---------------------------------------------------------------------------
// Split-bf16 MFMA GEMM (3-MFMA). Tile 128x64, BK=64, 4 waves.
// MODE 0: fp32+bias -> Cf; MODE 1: RoPE * (0.125*log2e) -> bf16 hi (Q);
// MODE 2: RoPE -> bf16 hi (K); MODE 3: plain -> bf16 hi [b,h,d,s] (V^T).
// ---------------------------------------------------------------------------
template<int MODE, bool WLO>
__global__ __launch_bounds__(256) void k_mgemm(const unsigned short* __restrict__ Ah_g,
                                               const unsigned short* __restrict__ Al_g,
                                               const unsigned short* __restrict__ Bh_g,
                                               const unsigned short* __restrict__ Bl_g,
                                               const float* __restrict__ bias,
                                               float* __restrict__ Cf,
                                               unsigned short* __restrict__ Ohi,
                                               unsigned short* __restrict__ Olo,
                                               const float* __restrict__ sin_t,
                                               const float* __restrict__ cos_t) {
    __shared__ unsigned short Ah[128 * 64];
    __shared__ unsigned short Al[128 * 64];
    __shared__ unsigned short Bh[64 * 64];
    __shared__ unsigned short Bl[64 * 64];
    const int tid = threadIdx.x;
    const int lane = tid & 63;
    const int w = tid >> 6;

    int bid = blockIdx.x;
    int wg = (bid & 7) * 64 + (bid >> 3);
    const int m0 = (wg >> 4) * 128;
    const int n0 = (wg & 15) * 64;

    size_t a_goff[4]; int a_ldst[4];
#pragma unroll
    for (int it = 0; it < 4; ++it) {
        int off = it * 4096 + w * 1024 + lane * 16;
        int row = off >> 7;
        int pg = (off >> 4) & 7;
        int lg = pg ^ (row & 7);
        a_goff[it] = (size_t)(m0 + row) * DMODEL + lg * 8;
        a_ldst[it] = it * 2048 + w * 512;
    }
    size_t b_goff[2]; int b_ldst[2];
#pragma unroll
    for (int it = 0; it < 2; ++it) {
        int off = it * 4096 + w * 1024 + lane * 16;
        int row = off >> 7;
        int pg = (off >> 4) & 7;
        int lg = pg ^ (row & 7);
        b_goff[it] = (size_t)(n0 + row) * DMODEL + lg * 8;
        b_ldst[it] = it * 2048 + w * 512;
    }

    int aoff[2][2], boff[4][2];
#pragma unroll
    for (int mf = 0; mf < 2; ++mf)
#pragma unroll
        for (int ks = 0; ks < 2; ++ks) {
            int row = w * 32 + mf * 16 + (lane & 15);
            int g = ks * 4 + (lane >> 4);
            aoff[mf][ks] = row * 64 + ((g ^ (row & 7)) * 8);
        }
#pragma unroll
    for (int nf = 0; nf < 4; ++nf)
#pragma unroll
        for (int ks = 0; ks < 2; ++ks) {
            int row = nf * 16 + (lane & 15);
            int g = ks * 4 + (lane >> 4);
            boff[nf][ks] = row * 64 + ((g ^ (row & 7)) * 8);
        }

    f32x4 acc[2][4];
#pragma unroll
    for (int mf = 0; mf < 2; ++mf)
#pragma unroll
        for (int nf = 0; nf < 4; ++nf) acc[mf][nf] = (f32x4){0.f, 0.f, 0.f, 0.f};

    for (int kt = 0; kt < 16; ++kt) {
        const int k0 = kt * 64;
#pragma unroll
        for (int it = 0; it < 4; ++it) {
            gl2lds16(Ah_g + a_goff[it] + k0, &Ah[a_ldst[it]]);
            gl2lds16(Al_g + a_goff[it] + k0, &Al[a_ldst[it]]);
        }
#pragma unroll
        for (int it = 0; it < 2; ++it) {
            gl2lds16(Bh_g + b_goff[it] + k0, &Bh[b_ldst[it]]);
            gl2lds16(Bl_g + b_goff[it] + k0, &Bl[b_ldst[it]]);
        }
        __syncthreads();
#pragma unroll
        for (int ks = 0; ks < 2; ++ks) {
            bf16x8 ah[2], al[2], bh[4], bl[4];
#pragma unroll
            for (int mf = 0; mf < 2; ++mf) {
                ah[mf] = *reinterpret_cast<const bf16x8*>(&Ah[aoff[mf][ks]]);
                al[mf] = *reinterpret_cast<const bf16x8*>(&Al[aoff[mf][ks]]);
            }
#pragma unroll
            for (int nf = 0; nf < 4; ++nf) {
                bh[nf] = *reinterpret_cast<const bf16x8*>(&Bh[boff[nf][ks]]);
                bl[nf] = *reinterpret_cast<const bf16x8*>(&Bl[boff[nf][ks]]);
            }
#pragma unroll
            for (int mf = 0; mf < 2; ++mf)
#pragma unroll
                for (int nf = 0; nf < 4; ++nf) {
                    acc[mf][nf] = __builtin_amdgcn_mfma_f32_16x16x32_bf16(al[mf], bh[nf], acc[mf][nf], 0, 0, 0);
                    acc[mf][nf] = __builtin_amdgcn_mfma_f32_16x16x32_bf16(ah[mf], bl[nf], acc[mf][nf], 0, 0, 0);
                    acc[mf][nf] = __builtin_amdgcn_mfma_f32_16x16x32_bf16(ah[mf], bh[nf], acc[mf][nf], 0, 0, 0);
                }
        }
        __syncthreads();
    }

    const int c = lane & 15;
    const int rq = lane >> 4;
    float bv[4];
#pragma unroll
    for (int nf = 0; nf < 4; ++nf) bv[nf] = bias[n0 + nf * 16 + c];

#pragma unroll
    for (int mf = 0; mf < 2; ++mf) {
        int mbase = m0 + w * 32 + mf * 16 + rq * 4;
        if (MODE == 0) {
#pragma unroll
            for (int nf = 0; nf < 4; ++nf)
#pragma unroll
                for (int r = 0; r < 4; ++r)
                    Cf[(size_t)(mbase + r) * DMODEL + n0 + nf * 16 + c] = acc[mf][nf][r] + bv[nf];
        } else if (MODE == 1 || MODE == 2) {
#pragma unroll
            for (int r = 0; r < 4; ++r) {
                int m = mbase + r;
                int srow = m & (SEQ - 1);
                float x0 = acc[mf][0][r] + bv[0];
                float x1 = acc[mf][1][r] + bv[1];
                float x2 = acc[mf][2][r] + bv[2];
                float x3 = acc[mf][3][r] + bv[3];
                float s0 = sin_t[srow * 32 + c],      c0 = cos_t[srow * 32 + c];
                float s1 = sin_t[srow * 32 + 16 + c], c1 = cos_t[srow * 32 + 16 + c];
                float o0 = c0 * x0 - s0 * x2;
                float o2 = s0 * x0 + c0 * x2;
                float o1 = c1 * x1 - s1 * x3;
                float o3 = s1 * x1 + c1 * x3;
                if (MODE == 1) {
                    const float qs = 0.18033688011112042f;   // 0.125*log2(e)
                    o0 *= qs; o1 *= qs; o2 *= qs; o3 *= qs;
                }
                float ov[4] = { o0, o1, o2, o3 };
                size_t base = (size_t)m * DMODEL + n0 + c;
#pragma unroll
                for (int nf = 0; nf < 4; ++nf) {
                    unsigned short h = f2bf(ov[nf]);
                    Ohi[base + nf * 16] = h;
                    if (WLO) Olo[base + nf * 16] = f2bf(ov[nf] - bf2f(h));
                }
            }
        } else {   // MODE 3: V^T [b,h,d,s] hi only
            int bb = mbase >> 11;
            int s = mbase & (SEQ - 1);
            int h = n0 >> 6;
#pragma unroll
            for (int nf = 0; nf < 4; ++nf) {
                ushort4 h4;
                float v0 = acc[mf][nf][0] + bv[nf];
                float v1 = acc[mf][nf][1] + bv[nf];
                float v2 = acc[mf][nf][2] + bv[nf];
                float v3 = acc[mf][nf][3] + bv[nf];
                h4.x = f2bf(v0); h4.y = f2bf(v1); h4.z = f2bf(v2); h4.w = f2bf(v3);
                int d = nf * 16 + c;
                size_t o = ((size_t)((bb * NH + h) * KD + d)) * SEQ + s;
                *reinterpret_cast<ushort4*>(&Ohi[o]) = h4;
            }
        }
    }
}

// ---------------------------------------------------------------------------
// Flash attention, bf16 MFMA, unnormalized softmax (p = 2^s, no max/rescale,
// deferred l-reduce). Swapped QK^T: mfma(K,Q) puts 4 consecutive t per lane
// -> cvt_pk_bf16 pairs + ds_write_b64 for P. 4 waves, 128 q-rows/block.
// ---------------------------------------------------------------------------
__global__ __launch_bounds__(256) void k_attn(const unsigned short* __restrict__ qhi,
                                              const unsigned short* __restrict__ khi,
                                              const unsigned short* __restrict__ vthi,
                                              unsigned short* __restrict__ ch,
                                              unsigned short* __restrict__ cl) {
    __shared__ unsigned short Kh[2][64 * 64];
    __shared__ unsigned short Vh[2][64 * 64];   // [d][t]
    __shared__ unsigned short Ps[4][32 * 64];

    const int tid  = threadIdx.x;
    const int lane = tid & 63;
    const int w    = tid >> 6;

    int bid = blockIdx.x;
    int wg  = (bid & 7) * 64 + (bid >> 3);
    const int qt = wg & 15;
    const int h  = (wg >> 4) & 15;
    const int b  = wg >> 8;
    const int q0 = qt * 128;

    // Q fragments (bf16, pre-scaled by 0.125*log2e)
    bf16x8 qf[2][2];   // [mf][ks]
#pragma unroll
    for (int mf = 0; mf < 2; ++mf)
#pragma unroll
        for (int ks = 0; ks < 2; ++ks) {
            int row = q0 + w * 32 + mf * 16 + (lane & 15);
            int d = ks * 32 + (lane >> 4) * 8;
            qf[mf][ks] = *reinterpret_cast<const bf16x8*>(
                qhi + ((size_t)(b * SEQ + row) * NH + h) * KD + d);
        }

    size_t gK[2], gV[2]; int ld_[2];
#pragma unroll
    for (int it = 0; it < 2; ++it) {
        int off = it * 4096 + tid * 16;
        int row = off >> 7;
        int pg = (off >> 4) & 7;
        int lg = pg ^ (row & 7);
        gK[it] = ((size_t)(b * SEQ + row) * NH + h) * KD + lg * 8;
        gV[it] = ((size_t)(b * NH + h) * KD + row) * SEQ + lg * 8;
        ld_[it] = it * 2048 + w * 512;
    }

    f32x4 acc[2][4];
    float l_part[2] = { 0.f, 0.f };
#pragma unroll
    for (int mf = 0; mf < 2; ++mf)
#pragma unroll
        for (int nf = 0; nf < 4; ++nf) acc[mf][nf] = (f32x4){0.f, 0.f, 0.f, 0.f};

#define STAGE(BUF, TT) do {                                                  \
        size_t kadv = (size_t)(TT) * 64 * NH * KD;                           \
        size_t vadv = (size_t)(TT) * 64;                                     \
        gl2lds16(khi  + gK[0] + kadv, &Kh[BUF][ld_[0]]);                     \
        gl2lds16(khi  + gK[1] + kadv, &Kh[BUF][ld_[1]]);                     \
        gl2lds16(vthi + gV[0] + vadv, &Vh[BUF][ld_[0]]);                     \
        gl2lds16(vthi + gV[1] + vadv, &Vh[BUF][ld_[1]]);                     \
    } while (0)

    STAGE(0, 0);

    for (int t = 0; t < 32; ++t) {
        const int cur = t & 1;
        if (t < 31) {
            STAGE(cur ^ 1, t + 1);
            asm volatile("s_waitcnt vmcnt(4)" ::: "memory");
        } else {
            asm volatile("s_waitcnt vmcnt(0)" ::: "memory");
        }
        __builtin_amdgcn_s_barrier();

        // ---- QK^T (swapped: A=K, B=Q; D col=q, row=t) ----
        f32x4 s[2][4];
#pragma unroll
        for (int mf = 0; mf < 2; ++mf)
#pragma unroll
            for (int nf = 0; nf < 4; ++nf) s[mf][nf] = (f32x4){0.f, 0.f, 0.f, 0.f};
#pragma unroll
        for (int nf = 0; nf < 4; ++nf) {
#pragma unroll
            for (int ks = 0; ks < 2; ++ks) {
                int trow = nf * 16 + (lane & 15);
                int koff = trow * 64 + (((ks * 4 + (lane >> 4)) ^ (trow & 7)) * 8);
                bf16x8 kf = *reinterpret_cast<const bf16x8*>(&Kh[cur][koff]);
#pragma unroll
                for (int mf = 0; mf < 2; ++mf)
                    s[mf][nf] = __builtin_amdgcn_mfma_f32_16x16x32_bf16(kf, qf[mf][ks], s[mf][nf], 0, 0, 0);
            }
        }

        // ---- p = 2^s ; accumulate l; pack P (4 consecutive t per lane) ----
#pragma unroll
        for (int mf = 0; mf < 2; ++mf) {
            int qloc = mf * 16 + (lane & 15);
#pragma unroll
            for (int nf = 0; nf < 4; ++nf) {
                float p0 = exp2_hw(s[mf][nf][0]);
                float p1 = exp2_hw(s[mf][nf][1]);
                float p2 = exp2_hw(s[mf][nf][2]);
                float p3 = exp2_hw(s[mf][nf][3]);
                l_part[mf] += (p0 + p1) + (p2 + p3);
                unsigned w01 = cvt_pk_bf16(p0, p1);
                unsigned w23 = cvt_pk_bf16(p2, p3);
                int tb = nf * 16 + (lane >> 4) * 4;
                int phys = tb ^ ((qloc & 7) << 3);
                *reinterpret_cast<uint2*>(&Ps[w][qloc * 64 + phys]) = make_uint2(w01, w23);
            }
        }

        // ---- PV ----
#pragma unroll
        for (int ks = 0; ks < 2; ++ks) {
            bf16x8 pa[2];
#pragma unroll
            for (int mf = 0; mf < 2; ++mf) {
                int row = mf * 16 + (lane & 15);
                int aoff = row * 64 + (((ks * 4 + (lane >> 4)) ^ (row & 7)) * 8);
                pa[mf] = *reinterpret_cast<const bf16x8*>(&Ps[w][aoff]);
            }
#pragma unroll
            for (int nf = 0; nf < 4; ++nf) {
                int drow = nf * 16 + (lane & 15);
                int voff = drow * 64 + (((ks * 4 + (lane >> 4)) ^ (drow & 7)) * 8);
                bf16x8 vf = *reinterpret_cast<const bf16x8*>(&Vh[cur][voff]);
#pragma unroll
                for (int mf = 0; mf < 2; ++mf)
                    acc[mf][nf] = __builtin_amdgcn_mfma_f32_16x16x32_bf16(pa[mf], vf, acc[mf][nf], 0, 0, 0);
            }
        }
        __builtin_amdgcn_s_barrier();
    }
#undef STAGE

    // ---- final l reduce (once) + normalize + store ctx bf16 hi/lo ----
#pragma unroll
    for (int mf = 0; mf < 2; ++mf) {
        l_part[mf] += __shfl_xor(l_part[mf], 16);
        l_part[mf] += __shfl_xor(l_part[mf], 32);
    }
#pragma unroll
    for (int mf = 0; mf < 2; ++mf) {
#pragma unroll
        for (int r = 0; r < 4; ++r) {
            float lsum = __shfl(l_part[mf], (lane >> 4) * 4 + r);
            float inv = 1.0f / lsum;
            int qg = q0 + w * 32 + mf * 16 + (lane >> 4) * 4 + r;
#pragma unroll
            for (int nf = 0; nf < 4; ++nf) {
                int d = nf * 16 + (lane & 15);
                float val = acc[mf][nf][r] * inv;
                size_t o = ((size_t)(b * SEQ + qg) * NH + h) * KD + d;
                unsigned short hv = f2bf(val);
                ch[o] = hv;
                cl[o] = f2bf(val - bf2f(hv));
            }
        }
    }
}

// ---------------------------------------------------------------------------
extern "C" void kernel_launch(void* const* d_in, const int* in_sizes, int n_in,
                              void* d_out, int out_size, void* d_ws, size_t ws_size,
                              hipStream_t stream) {
    const float* x  = (const float*)d_in[0];
    const float* Wq = (const float*)d_in[1];
    const float* bq = (const float*)d_in[2];
    const float* Wk = (const float*)d_in[3];
    const float* bk = (const float*)d_in[4];
    const float* Wv = (const float*)d_in[5];
    const float* bv = (const float*)d_in[6];
    const float* Wo = (const float*)d_in[7];
    const float* bo = (const float*)d_in[8];
    float* out = (float*)d_out;

    const size_t NE = (size_t)MROWS * DMODEL;   // 4M
    const size_t WE = (size_t)DMODEL * DMODEL;  // 1M
    float* ws    = (float*)d_ws;
    float* sin_t = ws;
    float* cos_t = sin_t + SEQ * 32;
    unsigned short* p = (unsigned short*)(cos_t + SEQ * 32);
    unsigned short* xh   = p; p += NE;
    unsigned short* xl   = p; p += NE;
    unsigned short* qh_  = p; p += NE;
    unsigned short* kh_  = p; p += NE;
    unsigned short* vth  = p; p += NE;
    unsigned short* wqh = p; p += WE;
    unsigned short* wql = p; p += WE;
    unsigned short* wkh = p; p += WE;
    unsigned short* wkl = p; p += WE;
    unsigned short* wvh = p; p += WE;
    unsigned short* wvl = p; p += WE;
    unsigned short* woh = p; p += WE;
    unsigned short* wol = p; p += WE;
    unsigned short* ctxh = xh;
    unsigned short* ctxl = xl;

    k_rope_tables<<<(SEQ * 32 + 255) / 256, 256, 0, stream>>>(sin_t, cos_t);
    k_cvt_x<<<(int)(NE / 4 / 256), 256, 0, stream>>>(x, xh, xl);
    dim3 tg(16, 16);
    k_cvt_wT<<<tg, 256, 0, stream>>>(Wq, wqh, wql);
    k_cvt_wT<<<tg, 256, 0, stream>>>(Wk, wkh, wkl);
    k_cvt_wT<<<tg, 256, 0, stream>>>(Wv, wvh, wvl);
    k_cvt_wT<<<tg, 256, 0, stream>>>(Wo, woh, wol);

    k_mgemm<1, false><<<512, 256, 0, stream>>>(xh, xl, wqh, wql, bq, nullptr, qh_, nullptr, sin_t, cos_t);
    k_mgemm<2, false><<<512, 256, 0, stream>>>(xh, xl, wkh, wkl, bk, nullptr, kh_, nullptr, sin_t, cos_t);
    k_mgemm<3, false><<<512, 256, 0, stream>>>(xh, xl, wvh, wvl, bv, nullptr, vth, nullptr, nullptr, nullptr);

    k_attn<<<512, 256, 0, stream>>>(qh_, kh_, vth, ctxh, ctxl);

    k_mgemm<0, false><<<512, 256, 0, stream>>>(ctxh, ctxl, woh, wol, bo, out, nullptr, nullptr, nullptr, nullptr);
}

// Round 8
// 165.694 us; speedup vs baseline: 8.0894x; 1.1430x over previous
//
#include <hip/hip_runtime.h>
#include <math.h>

#define NH 16
#define KD 64
#define DMODEL 1024
#define BATCH 2
#define SEQ 2048
#define MROWS (BATCH*SEQ)

typedef float f32x4 __attribute__((ext_vector_type(4)));
typedef __bf16 bf16x8 __attribute__((ext_vector_type(8)));

__device__ __forceinline__ unsigned short f2bf(float x) {
    union { float f; unsigned u; } a; a.f = x;
    unsigned r = a.u + 0x7fffu + ((a.u >> 16) & 1u);
    return (unsigned short)(r >> 16);
}
__device__ __forceinline__ float bf2f(unsigned short h) {
    union { unsigned u; float f; } a; a.u = ((unsigned)h) << 16; return a.f;
}
__device__ __forceinline__ unsigned cvt_pk_bf16(float lo, float hi) {
    unsigned r;
    asm("v_cvt_pk_bf16_f32 %0, %1, %2" : "=v"(r) : "v"(lo), "v"(hi));
    return r;
}
// 2^x on the VALU transcendental unit
__device__ __forceinline__ float exp2_hw(float x) {
    float r;
    asm("v_exp_f32 %0, %1" : "=v"(r) : "v"(x));
    return r;
}

__device__ __forceinline__ void gl2lds16(const void* gsrc, void* ldst) {
    __builtin_amdgcn_global_load_lds(
        (const __attribute__((address_space(1))) void*)gsrc,
        (__attribute__((address_space(3))) void*)ldst, 16, 0, 0);
}

// ---------------------------------------------------------------------------
__global__ __launch_bounds__(256) void k_rope_tables(float* __restrict__ sin_t,
                                                     float* __restrict__ cos_t) {
    int idx = blockIdx.x * 256 + threadIdx.x;
    if (idx >= SEQ * 32) return;
    int s = idx >> 5, i = idx & 31;
    float invf = expf((float)(2 * i) * (-logf(10000.0f) / (float)KD));
    float ang = (float)s * invf;
    sin_t[idx] = sinf(ang);
    cos_t[idx] = cosf(ang);
}

// ---------------------------------------------------------------------------
// x fp32 -> bf16 hi only (lo never consumed: QKV GEMMs use hi-A 2-split)
// ---------------------------------------------------------------------------
__global__ __launch_bounds__(256) void k_cvt_x(const float* __restrict__ x,
                                               unsigned short* __restrict__ xh) {
    int idx = blockIdx.x * 256 + threadIdx.x;
    float4 v = reinterpret_cast<const float4*>(x)[idx];
    ushort4 h;
    h.x = f2bf(v.x); h.y = f2bf(v.y); h.z = f2bf(v.z); h.w = f2bf(v.w);
    reinterpret_cast<ushort4*>(xh)[idx] = h;
}

// ---------------------------------------------------------------------------
// 4 weights [k][n] fp32 -> Wt [n][k] bf16 hi/lo pools (z = which weight)
// ---------------------------------------------------------------------------
__global__ __launch_bounds__(256) void k_cvt_w4(const float* __restrict__ W0,
                                                const float* __restrict__ W1,
                                                const float* __restrict__ W2,
                                                const float* __restrict__ W3,
                                                unsigned short* __restrict__ Th,
                                                unsigned short* __restrict__ Tl) {
    __shared__ float L[64][65];
    const int tid = threadIdx.x;
    const int n0 = blockIdx.x * 64, k0 = blockIdx.y * 64;
    const int z = blockIdx.z;
    const float* W = (z == 0) ? W0 : (z == 1) ? W1 : (z == 2) ? W2 : W3;
    const size_t zoff = (size_t)z * DMODEL * DMODEL;
#pragma unroll
    for (int it = 0; it < 4; ++it) {
        int idx = tid + it * 256;
        int r = idx >> 4;
        int c4 = (idx & 15) * 4;
        float4 v = *reinterpret_cast<const float4*>(&W[(size_t)(k0 + r) * DMODEL + n0 + c4]);
        L[r][c4 + 0] = v.x; L[r][c4 + 1] = v.y; L[r][c4 + 2] = v.z; L[r][c4 + 3] = v.w;
    }
    __syncthreads();
    int rn = tid >> 2;
    int ks = (tid & 3) * 16;
#pragma unroll
    for (int g = 0; g < 4; ++g) {
        ushort4 h, l;
        float v0 = L[ks + g * 4 + 0][rn];
        float v1 = L[ks + g * 4 + 1][rn];
        float v2 = L[ks + g * 4 + 2][rn];
        float v3 = L[ks + g * 4 + 3][rn];
        h.x = f2bf(v0); l.x = f2bf(v0 - bf2f(h.x));
        h.y = f2bf(v1); l.y = f2bf(v1 - bf2f(h.y));
        h.z = f2bf(v2); l.z = f2bf(v2 - bf2f(h.z));
        h.w = f2bf(v3); l.w = f2bf(v3 - bf2f(h.w));
        size_t o = zoff + (size_t)(n0 + rn) * DMODEL + k0 + ks + g * 4;
        *reinterpret_cast<ushort4*>(&Th[o]) = h;
        *reinterpret_cast<ushort4*>(&Tl[o]) = l;
    }
}

// ---------------------------------------------------------------------------
// Split-bf16 MFMA GEMM. Tile 128x64, BK=64, 4 waves.
// SPLITA=true: 3-MFMA (al·bh + ah·bl + ah·bh)  — O projection (fp32 out)
// SPLITA=false: 2-MFMA (ah·bl + ah·bh), no Al staging — QKV (bf16 out)
// MODE 0: fp32+bias -> Cf; MODE 1: RoPE * (0.125*log2e) -> bf16 hi (Q);
// MODE 2: RoPE -> bf16 hi (K); MODE 3: plain -> bf16 hi [b,h,d,s] (V^T).
// ---------------------------------------------------------------------------
template<int MODE, bool SPLITA>
__global__ __launch_bounds__(256) void k_mgemm(const unsigned short* __restrict__ Ah_g,
                                               const unsigned short* __restrict__ Al_g,
                                               const unsigned short* __restrict__ Bh_g,
                                               const unsigned short* __restrict__ Bl_g,
                                               const float* __restrict__ bias,
                                               float* __restrict__ Cf,
                                               unsigned short* __restrict__ Ohi,
                                               unsigned short* __restrict__ Olo,
                                               const float* __restrict__ sin_t,
                                               const float* __restrict__ cos_t) {
    __shared__ unsigned short Ah[128 * 64];
    __shared__ unsigned short Al[SPLITA ? 128 * 64 : 64];
    __shared__ unsigned short Bh[64 * 64];
    __shared__ unsigned short Bl[64 * 64];
    const int tid = threadIdx.x;
    const int lane = tid & 63;
    const int w = tid >> 6;

    int bid = blockIdx.x;
    int wg = (bid & 7) * 64 + (bid >> 3);
    const int m0 = (wg >> 4) * 128;
    const int n0 = (wg & 15) * 64;

    size_t a_goff[4]; int a_ldst[4];
#pragma unroll
    for (int it = 0; it < 4; ++it) {
        int off = it * 4096 + w * 1024 + lane * 16;
        int row = off >> 7;
        int pg = (off >> 4) & 7;
        int lg = pg ^ (row & 7);
        a_goff[it] = (size_t)(m0 + row) * DMODEL + lg * 8;
        a_ldst[it] = it * 2048 + w * 512;
    }
    size_t b_goff[2]; int b_ldst[2];
#pragma unroll
    for (int it = 0; it < 2; ++it) {
        int off = it * 4096 + w * 1024 + lane * 16;
        int row = off >> 7;
        int pg = (off >> 4) & 7;
        int lg = pg ^ (row & 7);
        b_goff[it] = (size_t)(n0 + row) * DMODEL + lg * 8;
        b_ldst[it] = it * 2048 + w * 512;
    }

    int aoff[2][2], boff[4][2];
#pragma unroll
    for (int mf = 0; mf < 2; ++mf)
#pragma unroll
        for (int ks = 0; ks < 2; ++ks) {
            int row = w * 32 + mf * 16 + (lane & 15);
            int g = ks * 4 + (lane >> 4);
            aoff[mf][ks] = row * 64 + ((g ^ (row & 7)) * 8);
        }
#pragma unroll
    for (int nf = 0; nf < 4; ++nf)
#pragma unroll
        for (int ks = 0; ks < 2; ++ks) {
            int row = nf * 16 + (lane & 15);
            int g = ks * 4 + (lane >> 4);
            boff[nf][ks] = row * 64 + ((g ^ (row & 7)) * 8);
        }

    f32x4 acc[2][4];
#pragma unroll
    for (int mf = 0; mf < 2; ++mf)
#pragma unroll
        for (int nf = 0; nf < 4; ++nf) acc[mf][nf] = (f32x4){0.f, 0.f, 0.f, 0.f};

    for (int kt = 0; kt < 16; ++kt) {
        const int k0 = kt * 64;
#pragma unroll
        for (int it = 0; it < 4; ++it) {
            gl2lds16(Ah_g + a_goff[it] + k0, &Ah[a_ldst[it]]);
            if (SPLITA) gl2lds16(Al_g + a_goff[it] + k0, &Al[a_ldst[it]]);
        }
#pragma unroll
        for (int it = 0; it < 2; ++it) {
            gl2lds16(Bh_g + b_goff[it] + k0, &Bh[b_ldst[it]]);
            gl2lds16(Bl_g + b_goff[it] + k0, &Bl[b_ldst[it]]);
        }
        __syncthreads();
#pragma unroll
        for (int ks = 0; ks < 2; ++ks) {
            bf16x8 ah[2], bh[4], bl[4];
#pragma unroll
            for (int mf = 0; mf < 2; ++mf)
                ah[mf] = *reinterpret_cast<const bf16x8*>(&Ah[aoff[mf][ks]]);
#pragma unroll
            for (int nf = 0; nf < 4; ++nf) {
                bh[nf] = *reinterpret_cast<const bf16x8*>(&Bh[boff[nf][ks]]);
                bl[nf] = *reinterpret_cast<const bf16x8*>(&Bl[boff[nf][ks]]);
            }
            if (SPLITA) {
                bf16x8 al[2];
#pragma unroll
                for (int mf = 0; mf < 2; ++mf)
                    al[mf] = *reinterpret_cast<const bf16x8*>(&Al[aoff[mf][ks]]);
#pragma unroll
                for (int mf = 0; mf < 2; ++mf)
#pragma unroll
                    for (int nf = 0; nf < 4; ++nf)
                        acc[mf][nf] = __builtin_amdgcn_mfma_f32_16x16x32_bf16(al[mf], bh[nf], acc[mf][nf], 0, 0, 0);
            }
#pragma unroll
            for (int mf = 0; mf < 2; ++mf)
#pragma unroll
                for (int nf = 0; nf < 4; ++nf) {
                    acc[mf][nf] = __builtin_amdgcn_mfma_f32_16x16x32_bf16(ah[mf], bl[nf], acc[mf][nf], 0, 0, 0);
                    acc[mf][nf] = __builtin_amdgcn_mfma_f32_16x16x32_bf16(ah[mf], bh[nf], acc[mf][nf], 0, 0, 0);
                }
        }
        __syncthreads();
    }

    const int c = lane & 15;
    const int rq = lane >> 4;
    float bv[4];
#pragma unroll
    for (int nf = 0; nf < 4; ++nf) bv[nf] = bias[n0 + nf * 16 + c];

#pragma unroll
    for (int mf = 0; mf < 2; ++mf) {
        int mbase = m0 + w * 32 + mf * 16 + rq * 4;
        if (MODE == 0) {
#pragma unroll
            for (int nf = 0; nf < 4; ++nf)
#pragma unroll
                for (int r = 0; r < 4; ++r)
                    Cf[(size_t)(mbase + r) * DMODEL + n0 + nf * 16 + c] = acc[mf][nf][r] + bv[nf];
        } else if (MODE == 1 || MODE == 2) {
#pragma unroll
            for (int r = 0; r < 4; ++r) {
                int m = mbase + r;
                int srow = m & (SEQ - 1);
                float x0 = acc[mf][0][r] + bv[0];
                float x1 = acc[mf][1][r] + bv[1];
                float x2 = acc[mf][2][r] + bv[2];
                float x3 = acc[mf][3][r] + bv[3];
                float s0 = sin_t[srow * 32 + c],      c0 = cos_t[srow * 32 + c];
                float s1 = sin_t[srow * 32 + 16 + c], c1 = cos_t[srow * 32 + 16 + c];
                float o0 = c0 * x0 - s0 * x2;
                float o2 = s0 * x0 + c0 * x2;
                float o1 = c1 * x1 - s1 * x3;
                float o3 = s1 * x1 + c1 * x3;
                if (MODE == 1) {
                    const float qs = 0.18033688011112042f;   // 0.125*log2(e)
                    o0 *= qs; o1 *= qs; o2 *= qs; o3 *= qs;
                }
                float ov[4] = { o0, o1, o2, o3 };
                size_t base = (size_t)m * DMODEL + n0 + c;
#pragma unroll
                for (int nf = 0; nf < 4; ++nf)
                    Ohi[base + nf * 16] = f2bf(ov[nf]);
            }
        } else {   // MODE 3: V^T [b,h,d,s] hi only
            int bb = mbase >> 11;
            int s = mbase & (SEQ - 1);
            int h = n0 >> 6;
#pragma unroll
            for (int nf = 0; nf < 4; ++nf) {
                ushort4 h4;
                float v0 = acc[mf][nf][0] + bv[nf];
                float v1 = acc[mf][nf][1] + bv[nf];
                float v2 = acc[mf][nf][2] + bv[nf];
                float v3 = acc[mf][nf][3] + bv[nf];
                h4.x = f2bf(v0); h4.y = f2bf(v1); h4.z = f2bf(v2); h4.w = f2bf(v3);
                int d = nf * 16 + c;
                size_t o = ((size_t)((bb * NH + h) * KD + d)) * SEQ + s;
                *reinterpret_cast<ushort4*>(&Ohi[o]) = h4;
            }
        }
    }
}

// ---------------------------------------------------------------------------
// Flash attention, bf16 MFMA, unnormalized softmax (p = 2^s, no max/rescale,
// deferred l-reduce). Swapped QK^T. 4 waves, 128 q-rows/block.
// ---------------------------------------------------------------------------
__global__ __launch_bounds__(256) void k_attn(const unsigned short* __restrict__ qhi,
                                              const unsigned short* __restrict__ khi,
                                              const unsigned short* __restrict__ vthi,
                                              unsigned short* __restrict__ ch,
                                              unsigned short* __restrict__ cl) {
    __shared__ unsigned short Kh[2][64 * 64];
    __shared__ unsigned short Vh[2][64 * 64];   // [d][t]
    __shared__ unsigned short Ps[4][32 * 64];

    const int tid  = threadIdx.x;
    const int lane = tid & 63;
    const int w    = tid >> 6;

    int bid = blockIdx.x;
    int wg  = (bid & 7) * 64 + (bid >> 3);
    const int qt = wg & 15;
    const int h  = (wg >> 4) & 15;
    const int b  = wg >> 8;
    const int q0 = qt * 128;

    // Q fragments (bf16, pre-scaled by 0.125*log2e)
    bf16x8 qf[2][2];   // [mf][ks]
#pragma unroll
    for (int mf = 0; mf < 2; ++mf)
#pragma unroll
        for (int ks = 0; ks < 2; ++ks) {
            int row = q0 + w * 32 + mf * 16 + (lane & 15);
            int d = ks * 32 + (lane >> 4) * 8;
            qf[mf][ks] = *reinterpret_cast<const bf16x8*>(
                qhi + ((size_t)(b * SEQ + row) * NH + h) * KD + d);
        }

    size_t gK[2], gV[2]; int ld_[2];
#pragma unroll
    for (int it = 0; it < 2; ++it) {
        int off = it * 4096 + tid * 16;
        int row = off >> 7;
        int pg = (off >> 4) & 7;
        int lg = pg ^ (row & 7);
        gK[it] = ((size_t)(b * SEQ + row) * NH + h) * KD + lg * 8;
        gV[it] = ((size_t)(b * NH + h) * KD + row) * SEQ + lg * 8;
        ld_[it] = it * 2048 + w * 512;
    }

    f32x4 acc[2][4];
    float l_part[2] = { 0.f, 0.f };
#pragma unroll
    for (int mf = 0; mf < 2; ++mf)
#pragma unroll
        for (int nf = 0; nf < 4; ++nf) acc[mf][nf] = (f32x4){0.f, 0.f, 0.f, 0.f};

#define STAGE(BUF, TT) do {                                                  \
        size_t kadv = (size_t)(TT) * 64 * NH * KD;                           \
        size_t vadv = (size_t)(TT) * 64;                                     \
        gl2lds16(khi  + gK[0] + kadv, &Kh[BUF][ld_[0]]);                     \
        gl2lds16(khi  + gK[1] + kadv, &Kh[BUF][ld_[1]]);                     \
        gl2lds16(vthi + gV[0] + vadv, &Vh[BUF][ld_[0]]);                     \
        gl2lds16(vthi + gV[1] + vadv, &Vh[BUF][ld_[1]]);                     \
    } while (0)

    STAGE(0, 0);

    for (int t = 0; t < 32; ++t) {
        const int cur = t & 1;
        if (t < 31) {
            STAGE(cur ^ 1, t + 1);
            asm volatile("s_waitcnt vmcnt(4)" ::: "memory");
        } else {
            asm volatile("s_waitcnt vmcnt(0)" ::: "memory");
        }
        __builtin_amdgcn_s_barrier();

        // ---- QK^T (swapped: A=K, B=Q; D col=q, row=t) ----
        f32x4 s[2][4];
#pragma unroll
        for (int mf = 0; mf < 2; ++mf)
#pragma unroll
            for (int nf = 0; nf < 4; ++nf) s[mf][nf] = (f32x4){0.f, 0.f, 0.f, 0.f};
#pragma unroll
        for (int nf = 0; nf < 4; ++nf) {
#pragma unroll
            for (int ks = 0; ks < 2; ++ks) {
                int trow = nf * 16 + (lane & 15);
                int koff = trow * 64 + (((ks * 4 + (lane >> 4)) ^ (trow & 7)) * 8);
                bf16x8 kf = *reinterpret_cast<const bf16x8*>(&Kh[cur][koff]);
#pragma unroll
                for (int mf = 0; mf < 2; ++mf)
                    s[mf][nf] = __builtin_amdgcn_mfma_f32_16x16x32_bf16(kf, qf[mf][ks], s[mf][nf], 0, 0, 0);
            }
        }

        // ---- p = 2^s ; accumulate l; pack P ----
#pragma unroll
        for (int mf = 0; mf < 2; ++mf) {
            int qloc = mf * 16 + (lane & 15);
#pragma unroll
            for (int nf = 0; nf < 4; ++nf) {
                float p0 = exp2_hw(s[mf][nf][0]);
                float p1 = exp2_hw(s[mf][nf][1]);
                float p2 = exp2_hw(s[mf][nf][2]);
                float p3 = exp2_hw(s[mf][nf][3]);
                l_part[mf] += (p0 + p1) + (p2 + p3);
                unsigned w01 = cvt_pk_bf16(p0, p1);
                unsigned w23 = cvt_pk_bf16(p2, p3);
                int tb = nf * 16 + (lane >> 4) * 4;
                int phys = tb ^ ((qloc & 7) << 3);
                *reinterpret_cast<uint2*>(&Ps[w][qloc * 64 + phys]) = make_uint2(w01, w23);
            }
        }

        // ---- PV ----
#pragma unroll
        for (int ks = 0; ks < 2; ++ks) {
            bf16x8 pa[2];
#pragma unroll
            for (int mf = 0; mf < 2; ++mf) {
                int row = mf * 16 + (lane & 15);
                int aoff = row * 64 + (((ks * 4 + (lane >> 4)) ^ (row & 7)) * 8);
                pa[mf] = *reinterpret_cast<const bf16x8*>(&Ps[w][aoff]);
            }
#pragma unroll
            for (int nf = 0; nf < 4; ++nf) {
                int drow = nf * 16 + (lane & 15);
                int voff = drow * 64 + (((ks * 4 + (lane >> 4)) ^ (drow & 7)) * 8);
                bf16x8 vf = *reinterpret_cast<const bf16x8*>(&Vh[cur][voff]);
#pragma unroll
                for (int mf = 0; mf < 2; ++mf)
                    acc[mf][nf] = __builtin_amdgcn_mfma_f32_16x16x32_bf16(pa[mf], vf, acc[mf][nf], 0, 0, 0);
            }
        }
        __builtin_amdgcn_s_barrier();
    }
#undef STAGE

    // ---- final l reduce + normalize + store ctx bf16 hi/lo ----
#pragma unroll
    for (int mf = 0; mf < 2; ++mf) {
        l_part[mf] += __shfl_xor(l_part[mf], 16);
        l_part[mf] += __shfl_xor(l_part[mf], 32);
    }
#pragma unroll
    for (int mf = 0; mf < 2; ++mf) {
#pragma unroll
        for (int r = 0; r < 4; ++r) {
            float lsum = __shfl(l_part[mf], (lane >> 4) * 4 + r);
            float inv = 1.0f / lsum;
            int qg = q0 + w * 32 + mf * 16 + (lane >> 4) * 4 + r;
#pragma unroll
            for (int nf = 0; nf < 4; ++nf) {
                int d = nf * 16 + (lane & 15);
                float val = acc[mf][nf][r] * inv;
                size_t o = ((size_t)(b * SEQ + qg) * NH + h) * KD + d;
                unsigned short hv = f2bf(val);
                ch[o] = hv;
                cl[o] = f2bf(val - bf2f(hv));
            }
        }
    }
}

// ---------------------------------------------------------------------------
extern "C" void kernel_launch(void* const* d_in, const int* in_sizes, int n_in,
                              void* d_out, int out_size, void* d_ws, size_t ws_size,
                              hipStream_t stream) {
    const float* x  = (const float*)d_in[0];
    const float* Wq = (const float*)d_in[1];
    const float* bq = (const float*)d_in[2];
    const float* Wk = (const float*)d_in[3];
    const float* bk = (const float*)d_in[4];
    const float* Wv = (const float*)d_in[5];
    const float* bv = (const float*)d_in[6];
    const float* Wo = (const float*)d_in[7];
    const float* bo = (const float*)d_in[8];
    float* out = (float*)d_out;

    const size_t NE = (size_t)MROWS * DMODEL;   // 4M
    const size_t WE = (size_t)DMODEL * DMODEL;  // 1M
    float* ws    = (float*)d_ws;
    float* sin_t = ws;
    float* cos_t = sin_t + SEQ * 32;
    unsigned short* p = (unsigned short*)(cos_t + SEQ * 32);
    unsigned short* xh   = p; p += NE;
    unsigned short* xl   = p; p += NE;   // used only as ctx_lo (attn writes it)
    unsigned short* qh_  = p; p += NE;
    unsigned short* kh_  = p; p += NE;
    unsigned short* vth  = p; p += NE;
    unsigned short* wth  = p; p += 4 * WE;   // hi pool: [Wq|Wk|Wv|Wo] transposed
    unsigned short* wtl  = p; p += 4 * WE;   // lo pool
    unsigned short* ctxh = xh;
    unsigned short* ctxl = xl;

    k_rope_tables<<<(SEQ * 32 + 255) / 256, 256, 0, stream>>>(sin_t, cos_t);
    k_cvt_x<<<(int)(NE / 4 / 256), 256, 0, stream>>>(x, xh);
    k_cvt_w4<<<dim3(16, 16, 4), 256, 0, stream>>>(Wq, Wk, Wv, Wo, wth, wtl);

    k_mgemm<1, false><<<512, 256, 0, stream>>>(xh, nullptr, wth + 0 * WE, wtl + 0 * WE, bq, nullptr, qh_, nullptr, sin_t, cos_t);
    k_mgemm<2, false><<<512, 256, 0, stream>>>(xh, nullptr, wth + 1 * WE, wtl + 1 * WE, bk, nullptr, kh_, nullptr, sin_t, cos_t);
    k_mgemm<3, false><<<512, 256, 0, stream>>>(xh, nullptr, wth + 2 * WE, wtl + 2 * WE, bv, nullptr, vth, nullptr, nullptr, nullptr);

    k_attn<<<512, 256, 0, stream>>>(qh_, kh_, vth, ctxh, ctxl);

    k_mgemm<0, true><<<512, 256, 0, stream>>>(ctxh, ctxl, wth + 3 * WE, wtl + 3 * WE, bo, out, nullptr, nullptr, nullptr, nullptr);
}